// Round 12
// baseline (999.222 us; speedup 1.0000x reference)
//
#include <hip/hip_runtime.h>
#include <stdint.h>

// Net_11587821765063: sequential SNN scan, T=1000 steps.
// Output = spike_out (T,1,COUT) float32 only.
//
// Round 31 (session r11): 3-DEEP SPECULATION + MERGE MACHINERY.
// r29/r30 proved visibility-lock: pace frozen at ~1765cy/step = (V+c)/2
// (V+c ~3530cy publish->consume), invariant to issue (-2.3x) and to publish
// mechanism (atomic-OR neutral). Only slack depth divides V. r25's 3-deep
// skeleton was VALIDATED (absmax 0) but issue-bound (4 dot+butterfly
// chains). This round grafts r26/r27's merge machinery onto it:
//  - eqA(w00=w01), eqB(w10=w11), eqX(w00=w10) flags with exact transitions;
//    arrays always materialized -> flags-true == bitwise-equal. Dot dedup:
//    all-equal common case runs 1 dot+butterfly instead of 4.
//  - updates specialized for all-spike / uniform-none cases (validated
//    identities), general VERBATIM r25 fmaf chain otherwise.
//  - protocol verbatim r25/r28: hb8 u32 publish @8B stride, scan16w,
//    retry, selfdec, d1 gated gather prefetch (slack 3).
// Narrow-ws fallback: proven r24 narrow path verbatim.

#define T_STEPS 1000
#define CIN     784
#define COUT    512
#define CPL     13            // columns per lane (64*13 = 832 >= 784)
#define VTHR_F   12500.0f
#define PROHIB_F 11250.0f

// narrow (proven) layout
#define N_NROW        512                     // 1B per row per step
#define N_CODE_OFFSET 524288                  // 512 KiB >= 512000 B of slots
// wide layout: 8B per row per step
#define W_ROWBYTES    4096                    // 512 rows * 8B stride
#define W_CODE_OFFSET 4194304                 // 4 MiB >= 4,096,000 B of slots
#define CODE_BYTES    (T_STEPS * 64 * 16)     // 1,024,000 B
#define W_TOTAL       ((size_t)W_CODE_OFFSET + (size_t)CODE_BYTES)

// ---- prep: zero slots and pack per-(t,lane) 16-byte code slot:
// byte j (j<13) encodes col = lane*13+j: bit0 = x[t][col], bits[2:1] = p.
template <bool WIDE>
__global__ __launch_bounds__(256) void prep_kernel(const int* __restrict__ x,
                                                   uint8_t* __restrict__ code,
                                                   uint8_t* __restrict__ slots) {
    int gid = blockIdx.x * blockDim.x + threadIdx.x;   // one per (t, lane)
    if (gid >= T_STEPS * 64) return;
    if constexpr (WIDE) {
        uint4 z = make_uint4(0u, 0u, 0u, 0u);
        uint4* s4 = (uint4*)slots;                      // 64000 x 64B = 4.096MB
        #pragma unroll
        for (int k = 0; k < 4; ++k) s4[(size_t)gid * 4 + k] = z;
    } else {
        ((uint2*)slots)[gid] = make_uint2(0u, 0u);      // 64000 x 8B
    }
    int t = gid >> 6;
    int lane = gid & 63;
    uint32_t wds[4] = {0u, 0u, 0u, 0u};
    #pragma unroll
    for (int j = 0; j < CPL; ++j) {
        int col = lane * CPL + j;
        uint32_t b = 0u;
        if (col < CIN) {
            int xc = x[t * CIN + col];
            int xp = (t > 0) ? x[(t - 1) * CIN + col] : 0;
            int p = xc ? 2 : ((t == 0) ? 1 : (xp ? 1 : 0));
            b = (uint32_t)((xc & 1) | (p << 1));
        }
        wds[j >> 2] |= b << ((j & 3) * 8);
    }
    ((uint4*)code)[gid] = make_uint4(wds[0], wds[1], wds[2], wds[3]);
}

// narrow scan: 8 row-bytes in one ull
__device__ __forceinline__ void scan8(unsigned long long gv, int kk,
                                      bool& anyset, bool& allp) {
    anyset = false; allp = true;
    #pragma unroll
    for (int i = 0; i < 8; ++i) {
        uint32_t b = (uint32_t)(gv >> (8 * i)) & 0xFFu;
        bool p = (b & 0xF0u) == 0xB0u;
        allp = allp && p;
        anyset = anyset || (p && (((b >> kk) & 1u) != 0u));
    }
}

// wide 3-deep scan: 8 slots (8B stride); low u16 = (0xB0 marker << 8) | hb8.
__device__ __forceinline__ void scan16w(const unsigned long long* g, int kk3,
                                        bool& anyset, bool& allp) {
    anyset = false; allp = true;
    #pragma unroll
    for (int i = 0; i < 8; ++i) {
        uint32_t v = (uint32_t)(g[i] & 0xFFFFu);
        bool p = (v >> 8) == 0xB0u;
        allp = allp && p;
        anyset = anyset || (p && (((v >> kk3) & 1u) != 0u));
    }
}

// bfe-based decode (r27): values identical to the byte-wise decode.
__device__ __forceinline__ void decode_code(const uint4& c, float* xf, float* pf) {
    uint32_t cwd[4] = {c.x, c.y, c.z, c.w};
    #pragma unroll
    for (int j = 0; j < CPL; ++j) {
        xf[j] = (float)((cwd[j >> 2] >> ((j & 3) * 8)) & 1u);
        pf[j] = (float)((cwd[j >> 2] >> ((j & 3) * 8 + 1)) & 0x7Fu);
    }
}

// ---- fast bit-exact butterfly building blocks ----
typedef unsigned uint2ev __attribute__((ext_vector_type(2)));

__device__ __forceinline__ float pl32_sum(float v) {
    unsigned a = __builtin_bit_cast(unsigned, v);
    unsigned b = a;
#if __has_builtin(__builtin_amdgcn_permlane32_swap)
    uint2ev r = __builtin_amdgcn_permlane32_swap(a, b, false, false);
    a = r.x; b = r.y;
#else
    asm volatile("v_permlane32_swap_b32 %0, %1" : "+v"(a), "+v"(b));
#endif
    return __builtin_bit_cast(float, a) + __builtin_bit_cast(float, b);
}

__device__ __forceinline__ float pl16_sum(float v) {
    unsigned a = __builtin_bit_cast(unsigned, v);
    unsigned b = a;
#if __has_builtin(__builtin_amdgcn_permlane16_swap)
    uint2ev r = __builtin_amdgcn_permlane16_swap(a, b, false, false);
    a = r.x; b = r.y;
#else
    asm volatile("v_permlane16_swap_b32 %0, %1" : "+v"(a), "+v"(b));
#endif
    return __builtin_bit_cast(float, a) + __builtin_bit_cast(float, b);
}

template <int CTRL>
__device__ __forceinline__ float dpp_xor_sum(float v) {
    int xi = __builtin_bit_cast(int, v);
    int t = __builtin_amdgcn_update_dpp(xi, xi, CTRL, 0xF, 0xF, false);
    return v + __builtin_bit_cast(float, t);
}

// stage 4 (xor4 within 16-lane rows) in pure DPP (validated r23)
__device__ __forceinline__ float dpp_xor4_sum(float v) {
    int xi = __builtin_bit_cast(int, v);
    int t1 = __builtin_amdgcn_update_dpp(xi, xi, 0x124, 0xF, 0x5, false);
    int t2 = __builtin_amdgcn_update_dpp(t1, xi, 0x12C, 0xF, 0xA, false);
    return v + __builtin_bit_cast(float, t2);
}

// full 64-lane sum, pairing bit-identical to the validated xor butterfly
__device__ __forceinline__ float wave_sum(float v) {
    v = pl32_sum(v);                  // stage 32
    v = pl16_sum(v);                  // stage 16
    v = dpp_xor_sum<0x128>(v);        // stage 8
    v = dpp_xor4_sum(v);              // stage 4
    v = dpp_xor_sum<0x4E>(v);         // stage 2
    v = dpp_xor_sum<0xB1>(v);         // stage 1
    return v;
}

__device__ __forceinline__ int rfl(bool b) {
    return __builtin_amdgcn_readfirstlane((int)b);
}

// ======================= 3-deep merged step =======================
// Worlds entering step u: (a,b) = (P[u-2], P[u-1]); w{a}{b}, mem{a}{b},
// ps{a}{b}=spike[u-1], pm{a}{b}=spike[u-2] over (P[u-3],P[u-2]),
// pm3/4/5 = P[u-3/4/5], hm1/2/3 = own hb8(u-1/2/3).
// eqA: w00==w01, eqB: w10==w11, eqX: w00==w10 (bitwise, guaranteed:
// arrays always materialized).
__device__ __forceinline__ void snn3_step(
    int u, int row, int lane,
    const uint4* __restrict__ code4, uint8_t* __restrict__ slots,
    float (&w00)[CPL], float (&w01)[CPL], float (&w10)[CPL], float (&w11)[CPL],
    float (&xfc)[CPL], float (&pfc)[CPL],
    float (&xfn)[CPL], float (&pfn)[CPL],
    uint4& cwn, uint4& cwl,
    unsigned long long (&gcur)[8], unsigned long long (&gnxt)[8],
    float& mem00, float& mem01, float& mem10, float& mem11,
    bool& ps00, bool& ps01, bool& ps10, bool& ps11,
    bool& pm00, bool& pm01, bool& pm10, bool& pm11,
    int& pm3, int& pm4, int& pm5,
    int& hm1, int& hm2, int& hm3,
    bool& eqA, bool& eqB, bool& eqX,
    uint32_t& myb)
{
    // ---- issue code load for u+2; selfdec from own history ----
    cwl = (u + 2 < T_STEPS) ? code4[(size_t)(u + 2) * 64 + lane]
                            : make_uint4(0u, 0u, 0u, 0u);
    const int kk3 = (pm5 << 2) | (pm4 << 1) | pm3;     // index into hb8(u-3)
    const bool selfdec = (u >= 3) && (((hm3 >> kk3) & 1) != 0);
    const unsigned long long* gl =
        (const unsigned long long*)(slots + (size_t)(u >= 3 ? u - 3 : 0) * W_ROWBYTES);
    // gather for this step was PREFETCHED into gcur at end of step u-1.

    // ---- dots with dedup (flags guarantee bitwise equality) ----
    float dot00, dot01, dot10, dot11;
    {
        float d = 0.0f;
        #pragma unroll
        for (int j = 0; j < CPL; ++j) d += xfc[j] * w00[j];
        dot00 = wave_sum(d);
    }
    if (rfl(eqA)) { dot01 = dot00; }
    else {
        float d = 0.0f;
        #pragma unroll
        for (int j = 0; j < CPL; ++j) d += xfc[j] * w01[j];
        dot01 = wave_sum(d);
    }
    if (rfl(eqX)) { dot10 = dot00; }
    else {
        float d = 0.0f;
        #pragma unroll
        for (int j = 0; j < CPL; ++j) d += xfc[j] * w10[j];
        dot10 = wave_sum(d);
    }
    if (rfl(eqB)) { dot11 = dot10; }
    else {
        float d = 0.0f;
        #pragma unroll
        for (int j = 0; j < CPL; ++j) d += xfc[j] * w11[j];
        dot11 = wave_sum(d);
    }

    // ---- pipelined decode of step u+1's codes ----
    decode_code(cwn, xfn, pfn);

    // ---- 8 hypotheses m[a][b][c] (verbatim r25) ----
    float sa00 = mem00 + dot00, sa01 = mem01 + dot01;
    float sa10 = mem10 + dot10, sa11 = mem11 + dot11;
    float m000 = fmaxf(sa00, 0.0f), m001 = fmaxf(sa00 - PROHIB_F, 0.0f);
    float m010 = fmaxf(sa01, 0.0f), m011 = fmaxf(sa01 - PROHIB_F, 0.0f);
    float m100 = fmaxf(sa10, 0.0f), m101 = fmaxf(sa10 - PROHIB_F, 0.0f);
    float m110 = fmaxf(sa11, 0.0f), m111 = fmaxf(sa11 - PROHIB_F, 0.0f);
    bool s000 = m000 >= VTHR_F, s001 = m001 >= VTHR_F;
    bool s010 = m010 >= VTHR_F, s011 = m011 >= VTHR_F;
    bool s100 = m100 >= VTHR_F, s101 = m101 >= VTHR_F;
    bool s110 = m110 >= VTHR_F, s111 = m111 >= VTHR_F;
    // bit index = (a<<2)|(b<<1)|c
    int hb = (s000 ? 1 : 0)  | (s001 ? 2 : 0)  | (s010 ? 4 : 0)  | (s011 ? 8 : 0)
           | (s100 ? 16 : 0) | (s101 ? 32 : 0) | (s110 ? 64 : 0) | (s111 ? 128 : 0);

    // ---- publish own row's hb8(u): u32 slot, marker byte 0xB0 ----
    if (lane == 0) {
        uint32_t* s32 = (uint32_t*)(slots + (size_t)u * W_ROWBYTES + (size_t)row * 8);
        __hip_atomic_store(s32, 0xB000u | (uint32_t)hb,
                           __ATOMIC_RELAXED, __HIP_MEMORY_SCOPE_AGENT);
    }

    // ---- resolve e = P[u-2] via hb8(u-3): prefetched gcur + retry ----
    int e = 0;
    if (u >= 3) {
        if (selfdec) {
            e = 1;
        } else {
            bool anyset, allp;
            scan16w(gcur, kk3, anyset, allp);
            if (__any((int)anyset)) { e = 1; }
            else if (__all((int)allp)) { e = 0; }
            else {
                for (;;) {
                    __builtin_amdgcn_s_sleep(1);       // backoff (rare path)
                    #pragma unroll
                    for (int i = 0; i < 8; ++i)
                        gcur[i] = __hip_atomic_load(&gl[8 * lane + i],
                                                    __ATOMIC_RELAXED,
                                                    __HIP_MEMORY_SCOPE_AGENT);
                    scan16w(gcur, kk3, anyset, allp);
                    if (__any((int)anyset)) { e = 1; break; }
                    if (__all((int)allp)) { e = 0; break; }
                }
            }
        }
    }

    // ---- record output bit for v = u-2: spike[u-2] = pm[P[u-3]][e] ----
    if (u >= 2) {
        bool sv = pm3 ? (e ? pm11 : pm10) : (e ? pm01 : pm00);
        int v = u - 2;
        if ((v & 63) == lane) myb |= (sv ? 1u : 0u) << (v >> 6);
    }

    // ---- collapse a=e; new worlds (b,c) = (P[u-1], P[u]) (verbatim) ----
    float nm00 = e ? m100 : m000;      // m[e][0][0]
    float nm01 = e ? m101 : m001;
    float nm10 = e ? m110 : m010;
    float nm11 = e ? m111 : m011;
    bool ns00 = e ? s100 : s000;
    bool ns01 = e ? s101 : s001;
    bool ns10 = e ? s110 : s010;
    bool ns11 = e ? s111 : s011;
    bool sp0 = e ? ps10 : ps00;        // spike[u-1], world b=0
    bool sp1 = e ? ps11 : ps01;        // spike[u-1], world b=1

    mem00 = ns00 ? 0.0f : nm00;
    mem01 = ns01 ? 0.0f : nm01;
    mem10 = ns10 ? 0.0f : nm10;
    mem11 = ns11 ? 0.0f : nm11;

    // ---- weight updates: specialized common cases, general verbatim else.
    // All arrays ALWAYS materialized (read bases b0/b1 before any write).
    const bool all_spike = ns00 && ns01 && ns10 && ns11;
    const bool no_spike  = !ns00 && !ns01 && !ns10 && !ns11;
    if (rfl(all_spike)) {
        #pragma unroll
        for (int j = 0; j < CPL; ++j) {
            float b0 = e ? w10[j] : w00[j];
            float b1 = e ? w11[j] : w01[j];
            float v0 = fminf(pfc[j] + b0, 127.0f);
            float v1 = fminf(pfc[j] + b1, 127.0f);
            w00[j] = v0; w01[j] = v0;
            w10[j] = v1; w11[j] = v1;
        }
    } else if (rfl(no_spike)) {
        // depression iff sprv; per-pair uniform (both worlds in a pair
        // share sprv), so each pair gets one op.
        if (rfl(sp0)) {
            if (rfl(sp1)) {
                #pragma unroll
                for (int j = 0; j < CPL; ++j) {
                    float b0 = e ? w10[j] : w00[j];
                    float b1 = e ? w11[j] : w01[j];
                    float v0 = fmaxf(b0 - xfc[j], 0.0f);
                    float v1 = fmaxf(b1 - xfc[j], 0.0f);
                    w00[j] = v0; w01[j] = v0;
                    w10[j] = v1; w11[j] = v1;
                }
            } else {
                #pragma unroll
                for (int j = 0; j < CPL; ++j) {
                    float b0 = e ? w10[j] : w00[j];
                    float b1 = e ? w11[j] : w01[j];
                    float v0 = fmaxf(b0 - xfc[j], 0.0f);
                    w00[j] = v0; w01[j] = v0;
                    w10[j] = b1; w11[j] = b1;
                }
            }
        } else {
            if (rfl(sp1)) {
                #pragma unroll
                for (int j = 0; j < CPL; ++j) {
                    float b0 = e ? w10[j] : w00[j];
                    float b1 = e ? w11[j] : w01[j];
                    float v1 = fmaxf(b1 - xfc[j], 0.0f);
                    w00[j] = b0; w01[j] = b0;
                    w10[j] = v1; w11[j] = v1;
                }
            } else {
                #pragma unroll
                for (int j = 0; j < CPL; ++j) {
                    float b0 = e ? w10[j] : w00[j];
                    float b1 = e ? w11[j] : w01[j];
                    w00[j] = b0; w01[j] = b0;
                    w10[j] = b1; w11[j] = b1;
                }
            }
        }
    } else {
        // general verbatim r25 4-chain (bit-exact reference form)
        float sf00 = ns00 ? 1.0f : 0.0f, sf01 = ns01 ? 1.0f : 0.0f;
        float sf10 = ns10 ? 1.0f : 0.0f, sf11 = ns11 ? 1.0f : 0.0f;
        float df00 = (!ns00 && sp0) ? 1.0f : 0.0f;
        float df01 = (!ns01 && sp0) ? 1.0f : 0.0f;
        float df10 = (!ns10 && sp1) ? 1.0f : 0.0f;
        float df11 = (!ns11 && sp1) ? 1.0f : 0.0f;
        #pragma unroll
        for (int j = 0; j < CPL; ++j) {
            float b0 = e ? w10[j] : w00[j];
            float b1 = e ? w11[j] : w01[j];
            float t00 = fminf(fmaf(sf00, pfc[j], b0), 127.0f);
            w00[j] = fmaxf(fmaf(-df00, xfc[j], t00), 0.0f);
            float t01 = fminf(fmaf(sf01, pfc[j], b0), 127.0f);
            w01[j] = fmaxf(fmaf(-df01, xfc[j], t01), 0.0f);
            float t10 = fminf(fmaf(sf10, pfc[j], b1), 127.0f);
            w10[j] = fmaxf(fmaf(-df10, xfc[j], t10), 0.0f);
            float t11 = fminf(fmaf(sf11, pfc[j], b1), 127.0f);
            w11[j] = fmaxf(fmaf(-df11, xfc[j], t11), 0.0f);
        }
    }

    // ---- eq flag transitions (exact; use OLD eqA/eqB for eqX) ----
    {
        bool baseEq = e ? eqB : eqA;       // b0 == b1 bitwise
        bool eqA_n = (ns00 == ns01);
        bool eqB_n = (ns10 == ns11);
        bool eqX_n = baseEq && (ns00 == ns10) && (ns00 || (sp0 == sp1));
        eqA = eqA_n; eqB = eqB_n; eqX = eqX_n;
    }

    // ---- rotate state (verbatim r25) ----
    pm00 = ps00; pm01 = ps01; pm10 = ps10; pm11 = ps11;
    ps00 = ns00; ps01 = ns01; ps10 = ns10; ps11 = ns11;
    pm5 = pm4; pm4 = pm3; pm3 = e;
    hm3 = hm2; hm2 = hm1; hm1 = hb;

    // ---- distance-1 gated gather prefetch for step u+1 ----
    // selfdec(u+1) formula with rotated state == top-of-(u+1) formula.
    if (u + 1 < T_STEPS && u >= 2) {          // (u+1) >= 3
        const int kk3n = (pm5 << 2) | (pm4 << 1) | pm3;
        if (((hm3 >> kk3n) & 1) == 0) {
            const unsigned long long* glp =
                (const unsigned long long*)(slots + (size_t)(u - 2) * W_ROWBYTES);
            #pragma unroll
            for (int i = 0; i < 8; ++i)
                gnxt[i] = __hip_atomic_load(&glp[8 * lane + i], __ATOMIC_RELAXED,
                                            __HIP_MEMORY_SCOPE_AGENT);
        }
    }
}

__global__ __launch_bounds__(128, 1) void snn3_kernel(const float* __restrict__ weight,
                                                      const uint8_t* __restrict__ code,
                                                      uint8_t* __restrict__ slots,
                                                      float* __restrict__ out) {
    const int tid  = threadIdx.x;
    const int wave = tid >> 6;
    const int lane = tid & 63;
    const int row  = blockIdx.x * 2 + wave;    // 512 autonomous waves, 256 CUs

    float w00[CPL], w01[CPL], w10[CPL], w11[CPL];
    #pragma unroll
    for (int j = 0; j < CPL; ++j) {
        int col = lane * CPL + j;
        float v = (col < CIN) ? weight[row * CIN + col] : 0.0f;
        w00[j] = v; w01[j] = v; w10[j] = v; w11[j] = v;
    }

    const uint4* code4 = (const uint4*)code;

    float xf0[CPL], pf0[CPL], xf1[CPL], pf1[CPL];
    {
        uint4 c0 = code4[lane];
        decode_code(c0, xf0, pf0);
    }
    uint4 cwA = code4[64 + lane];
    uint4 cwB = make_uint4(0u, 0u, 0u, 0u);

    unsigned long long gA[8], gB[8];
    #pragma unroll
    for (int i = 0; i < 8; ++i) { gA[i] = 0ull; gB[i] = 0ull; }

    float mem00 = 0.0f, mem01 = 0.0f, mem10 = 0.0f, mem11 = 0.0f;
    bool ps00 = true, ps01 = true, ps10 = true, ps11 = true;  // spike(-1)=true
    bool pm00 = true, pm01 = true, pm10 = true, pm11 = true;
    int pm3 = 0, pm4 = 0, pm5 = 0;
    int hm1 = 0, hm2 = 0, hm3 = 0;
    bool eqA = true, eqB = true, eqX = true;   // all arrays identical at start
    uint32_t myb = 0u;

    for (int u = 0; u < T_STEPS; u += 2) {
        snn3_step(u,     row, lane, code4, slots, w00, w01, w10, w11,
                  xf0, pf0, xf1, pf1, cwA, cwB, gA, gB,
                  mem00, mem01, mem10, mem11,
                  ps00, ps01, ps10, ps11, pm00, pm01, pm10, pm11,
                  pm3, pm4, pm5, hm1, hm2, hm3, eqA, eqB, eqX, myb);
        snn3_step(u + 1, row, lane, code4, slots, w00, w01, w10, w11,
                  xf1, pf1, xf0, pf0, cwB, cwA, gB, gA,
                  mem00, mem01, mem10, mem11,
                  ps00, ps01, ps10, ps11, pm00, pm01, pm10, pm11,
                  pm3, pm4, pm5, hm1, hm2, hm3, eqA, eqB, eqX, myb);
    }

    // ---- epilogue (verbatim r25): resolve P[T-2] then P[T-1] ----
    {
        const int kk3 = (pm5 << 2) | (pm4 << 1) | pm3;
        int e1;
        if (((hm3 >> kk3) & 1) != 0) {
            e1 = 1;
        } else {
            const unsigned long long* gl =
                (const unsigned long long*)(slots + (size_t)(T_STEPS - 3) * W_ROWBYTES);
            for (;;) {
                unsigned long long g[8];
                #pragma unroll
                for (int i = 0; i < 8; ++i)
                    g[i] = __hip_atomic_load(&gl[8 * lane + i], __ATOMIC_RELAXED,
                                             __HIP_MEMORY_SCOPE_AGENT);
                bool anyset, allp;
                scan16w(g, kk3, anyset, allp);
                if (__any((int)anyset)) { e1 = 1; break; }
                if (__all((int)allp)) { e1 = 0; break; }
                __builtin_amdgcn_s_sleep(1);
            }
        }
        {   // spike[T-2] = pm[P[T-3]][e1]
            bool sv = pm3 ? (e1 ? pm11 : pm10) : (e1 ? pm01 : pm00);
            int v = T_STEPS - 2;
            if ((v & 63) == lane) myb |= (sv ? 1u : 0u) << (v >> 6);
        }
        const int kk3b = (pm4 << 2) | (pm3 << 1) | e1;
        int e2;
        if (((hm2 >> kk3b) & 1) != 0) {
            e2 = 1;
        } else {
            const unsigned long long* gl =
                (const unsigned long long*)(slots + (size_t)(T_STEPS - 2) * W_ROWBYTES);
            for (;;) {
                unsigned long long g[8];
                #pragma unroll
                for (int i = 0; i < 8; ++i)
                    g[i] = __hip_atomic_load(&gl[8 * lane + i], __ATOMIC_RELAXED,
                                             __HIP_MEMORY_SCOPE_AGENT);
                bool anyset, allp;
                scan16w(g, kk3b, anyset, allp);
                if (__any((int)anyset)) { e2 = 1; break; }
                if (__all((int)allp)) { e2 = 0; break; }
                __builtin_amdgcn_s_sleep(1);
            }
        }
        {   // spike[T-1] = ps[e1][e2]
            bool sv = e1 ? (e2 ? ps11 : ps10) : (e2 ? ps01 : ps00);
            int v = T_STEPS - 1;
            if ((v & 63) == lane) myb |= (sv ? 1u : 0u) << (v >> 6);
        }
        #pragma unroll
        for (int b = 0; b < 16; ++b) {
            int s = b * 64 + lane;
            if (s < T_STEPS)
                out[(size_t)s * COUT + row] = (float)((myb >> b) & 1u);
        }
    }
}

// ======================= narrow fallback (proven r24 narrow) =======================
__device__ __forceinline__ void snn_step_n(
    int u, int row, int lane,
    const uint4* __restrict__ code4, uint8_t* __restrict__ slots,
    float (&wA)[CPL], float (&wB)[CPL],
    float (&xfc)[CPL], float (&pfc)[CPL],
    float (&xfn)[CPL], float (&pfn)[CPL],
    uint4& cwn, uint4& cwl,
    float& memA, float& memB, bool& psA, bool& psB,
    int& p2, int& p3, int& hb_m1, int& hb_m2,
    uint32_t& myb)
{
    cwl = (u + 2 < T_STEPS) ? code4[(size_t)(u + 2) * 64 + lane]
                            : make_uint4(0u, 0u, 0u, 0u);
    const int kk = (p3 << 1) | p2;
    const bool selfdec = (u >= 2) && (((hb_m2 >> kk) & 1) != 0);
    const unsigned long long* gl =
        (const unsigned long long*)(slots + (size_t)(u >= 2 ? u - 2 : 0) * N_NROW);
    unsigned long long gv = 0xB0B0B0B0B0B0B0B0ull;
    if (u >= 2 && !selfdec)
        gv = __hip_atomic_load(&gl[lane], __ATOMIC_RELAXED,
                               __HIP_MEMORY_SCOPE_AGENT);

    float dA = 0.0f, dB = 0.0f;
    #pragma unroll
    for (int j = 0; j < CPL; ++j) { dA += xfc[j] * wA[j]; dB += xfc[j] * wB[j]; }
    float dotA = wave_sum(dA);
    float dotB = wave_sum(dB);

    decode_code(cwn, xfn, pfn);

    float sa = memA + dotA;
    float sb = memB + dotB;
    float m00 = fmaxf(sa, 0.0f), m01 = fmaxf(sa - PROHIB_F, 0.0f);
    float m10 = fmaxf(sb, 0.0f), m11 = fmaxf(sb - PROHIB_F, 0.0f);
    bool s00 = m00 >= VTHR_F, s01 = m01 >= VTHR_F;
    bool s10 = m10 >= VTHR_F, s11 = m11 >= VTHR_F;
    int hb = (s00 ? 1 : 0) | (s01 ? 2 : 0) | (s10 ? 4 : 0) | (s11 ? 8 : 0);

    if (lane == 0)
        __hip_atomic_store(&slots[(size_t)u * N_NROW + row],
                           (uint8_t)(0xB0u | (uint32_t)hb),
                           __ATOMIC_RELAXED, __HIP_MEMORY_SCOPE_AGENT);

    int bst = 0;
    if (u >= 2) {
        if (selfdec) {
            bst = 1;
        } else {
            for (;;) {
                bool anyset, allp;
                scan8(gv, kk, anyset, allp);
                if (__any((int)anyset)) { bst = 1; break; }
                if (__all((int)allp)) { bst = 0; break; }
                __builtin_amdgcn_s_sleep(1);
                gv = __hip_atomic_load(&gl[lane], __ATOMIC_RELAXED,
                                       __HIP_MEMORY_SCOPE_AGENT);
            }
        }
    }
    p3 = p2; p2 = bst;
    hb_m2 = hb_m1; hb_m1 = hb;

    bool sprv = bst ? psB : psA;
    bool sc0  = bst ? s10 : s00;
    bool sc1  = bst ? s11 : s01;
    float mc0 = bst ? m10 : m00;
    float mc1 = bst ? m11 : m01;

    if (u >= 1) {
        int v = u - 1;
        if ((v & 63) == lane) myb |= (sprv ? 1u : 0u) << (v >> 6);
    }

    memA = sc0 ? 0.0f : mc0;
    memB = sc1 ? 0.0f : mc1;

    float s0f = sc0 ? 1.0f : 0.0f;
    float s1f = sc1 ? 1.0f : 0.0f;
    float d0f = (!sc0 && sprv) ? 1.0f : 0.0f;
    float d1f = (!sc1 && sprv) ? 1.0f : 0.0f;
    #pragma unroll
    for (int j = 0; j < CPL; ++j) {
        float base = bst ? wB[j] : wA[j];
        float ta = fminf(fmaf(s0f, pfc[j], base), 127.0f);
        wA[j] = fmaxf(fmaf(-d0f, xfc[j], ta), 0.0f);
        float tb = fminf(fmaf(s1f, pfc[j], base), 127.0f);
        wB[j] = fmaxf(fmaf(-d1f, xfc[j], tb), 0.0f);
    }
    psA = sc0; psB = sc1;
}

__global__ __launch_bounds__(128, 1) void snn_kernel_n(const float* __restrict__ weight,
                                                       const uint8_t* __restrict__ code,
                                                       uint8_t* __restrict__ slots,
                                                       float* __restrict__ out) {
    const int tid  = threadIdx.x;
    const int wave = tid >> 6;
    const int lane = tid & 63;
    const int row  = blockIdx.x * 2 + wave;

    float wA[CPL], wB[CPL];
    #pragma unroll
    for (int j = 0; j < CPL; ++j) {
        int col = lane * CPL + j;
        float v = (col < CIN) ? weight[row * CIN + col] : 0.0f;
        wA[j] = v; wB[j] = v;
    }

    const uint4* code4 = (const uint4*)code;
    float xf0[CPL], pf0[CPL], xf1[CPL], pf1[CPL];
    {
        uint4 c0 = code4[lane];
        decode_code(c0, xf0, pf0);
    }
    uint4 cwA = code4[64 + lane];
    uint4 cwB = make_uint4(0u, 0u, 0u, 0u);

    float memA = 0.0f, memB = 0.0f;
    bool  psA = true, psB = true;
    int p2 = 0, p3 = 0;
    int hb_m1 = 0, hb_m2 = 0;
    uint32_t myb = 0u;

    for (int u = 0; u < T_STEPS; u += 2) {
        snn_step_n(u,     row, lane, code4, slots, wA, wB,
                   xf0, pf0, xf1, pf1, cwA, cwB,
                   memA, memB, psA, psB, p2, p3, hb_m1, hb_m2, myb);
        snn_step_n(u + 1, row, lane, code4, slots, wA, wB,
                   xf1, pf1, xf0, pf0, cwB, cwA,
                   memA, memB, psA, psB, p2, p3, hb_m1, hb_m2, myb);
    }

    {
        const int kk = (p3 << 1) | p2;
        int cst;
        if (((hb_m2 >> kk) & 1) != 0) {
            cst = 1;
        } else {
            const unsigned long long* gl2 =
                (const unsigned long long*)(slots + (size_t)(T_STEPS - 2) * N_NROW);
            unsigned long long gv2;
            for (;;) {
                gv2 = __hip_atomic_load(&gl2[lane], __ATOMIC_RELAXED,
                                        __HIP_MEMORY_SCOPE_AGENT);
                bool anyset, allp;
                scan8(gv2, kk, anyset, allp);
                if (__any((int)anyset)) { cst = 1; break; }
                if (__all((int)allp)) { cst = 0; break; }
                __builtin_amdgcn_s_sleep(1);
            }
        }
        bool sr = cst ? psB : psA;
        {
            int v = T_STEPS - 1;
            if ((v & 63) == lane) myb |= (sr ? 1u : 0u) << (v >> 6);
        }
        #pragma unroll
        for (int b = 0; b < 16; ++b) {
            int s = b * 64 + lane;
            if (s < T_STEPS)
                out[(size_t)s * COUT + row] = (float)((myb >> b) & 1u);
        }
    }
}

extern "C" void kernel_launch(void* const* d_in, const int* in_sizes, int n_in,
                              void* d_out, int out_size, void* d_ws, size_t ws_size,
                              hipStream_t stream) {
    const int*   x      = (const int*)d_in[0];     // (T,1,CIN) int32
    const float* weight = (const float*)d_in[1];   // (COUT,CIN) f32
    float* out = (float*)d_out;                    // (T,1,COUT) f32

    int prep_threads = T_STEPS * 64;
    int prep_blocks = (prep_threads + 255) / 256;
    if (ws_size >= W_TOTAL) {
        uint8_t* slots = (uint8_t*)d_ws;
        uint8_t* code  = (uint8_t*)d_ws + W_CODE_OFFSET;
        prep_kernel<true><<<prep_blocks, 256, 0, stream>>>(x, code, slots);
        snn3_kernel<<<256, 128, 0, stream>>>(weight, code, slots, out);
    } else {
        uint8_t* slots = (uint8_t*)d_ws;
        uint8_t* code  = (uint8_t*)d_ws + N_CODE_OFFSET;
        prep_kernel<false><<<prep_blocks, 256, 0, stream>>>(x, code, slots);
        snn_kernel_n<<<256, 128, 0, stream>>>(weight, code, slots, out);
    }
}

// Round 13
// 922.396 us; speedup vs baseline: 1.0833x; 1.0833x over previous
//
#include <hip/hip_runtime.h>
#include <stdint.h>

// Net_11587821765063: sequential SNN scan, T=1000 steps.
// Output = spike_out (T,1,COUT) float32 only.
//
// Round 32 (session r12): r28 champion body VERBATIM; GEOMETRY-ONLY change.
// Consolidated pace model over 8 kernels: pace ~= 2*issue + ~1000cy. The 2x
// factor + ~1000cy residual are intra-wave stalls (dep-chain latency 4cy/op,
// ~8-10 taken-branch refills, waitcnt) of a LONE WAVE PER SIMD -- every
// config so far (128x256, 256x128) spreads block waves round-robin over 4
// SIMDs = 1 wave/SIMD. This round: 64 blocks x 512 threads = 8 waves/block
// = 2 WAVES/SIMD (row = blockIdx*8 + wave; still exactly 512 co-resident
// waves, 64 blocks <= 256 CUs -> deadlock-freedom intact). Wave A's stall
// bubbles are filled by wave B's independent instructions; per-SIMD issue
// per step 2x380=760 busy cy -> pace can fall toward ~1100-1300cy.
// Kernel body byte-identical r28 (d1 gated gather prefetch, weq worlds,
// specialized updates, bfe decode, publish 0xB0|hb @8B stride, scan8w,
// retry, selfdec). Narrow-ws fallback: proven r24 narrow path verbatim.

#define T_STEPS 1000
#define CIN     784
#define COUT    512
#define CPL     13            // columns per lane (64*13 = 832 >= 784)
#define VTHR_F   12500.0f
#define PROHIB_F 11250.0f

// narrow (proven) layout
#define N_NROW        512                     // 1B per row per step
#define N_CODE_OFFSET 524288                  // 512 KiB >= 512000 B of slots
// wide layout (proven r24/r28): 8B per row per step
#define W_ROWBYTES    4096                    // 512 rows * 8B stride
#define W_CODE_OFFSET 4194304                 // 4 MiB >= 4,096,000 B of slots
#define CODE_BYTES    (T_STEPS * 64 * 16)     // 1,024,000 B
#define W_TOTAL       ((size_t)W_CODE_OFFSET + (size_t)CODE_BYTES)

// ---- prep: zero slots and pack per-(t,lane) 16-byte code slot:
// byte j (j<13) encodes col = lane*13+j: bit0 = x[t][col], bits[2:1] = p.
template <bool WIDE>
__global__ __launch_bounds__(256) void prep_kernel(const int* __restrict__ x,
                                                   uint8_t* __restrict__ code,
                                                   uint8_t* __restrict__ slots) {
    int gid = blockIdx.x * blockDim.x + threadIdx.x;   // one per (t, lane)
    if (gid >= T_STEPS * 64) return;
    if constexpr (WIDE) {
        uint4 z = make_uint4(0u, 0u, 0u, 0u);
        uint4* s4 = (uint4*)slots;                      // 64000 x 64B = 4.096MB
        #pragma unroll
        for (int k = 0; k < 4; ++k) s4[(size_t)gid * 4 + k] = z;
    } else {
        ((uint2*)slots)[gid] = make_uint2(0u, 0u);      // 64000 x 8B
    }
    int t = gid >> 6;
    int lane = gid & 63;
    uint32_t wds[4] = {0u, 0u, 0u, 0u};
    #pragma unroll
    for (int j = 0; j < CPL; ++j) {
        int col = lane * CPL + j;
        uint32_t b = 0u;
        if (col < CIN) {
            int xc = x[t * CIN + col];
            int xp = (t > 0) ? x[(t - 1) * CIN + col] : 0;
            int p = xc ? 2 : ((t == 0) ? 1 : (xp ? 1 : 0));
            b = (uint32_t)((xc & 1) | (p << 1));
        }
        wds[j >> 2] |= b << ((j & 3) * 8);
    }
    ((uint4*)code)[gid] = make_uint4(wds[0], wds[1], wds[2], wds[3]);
}

// narrow scan: 8 row-bytes in one ull
__device__ __forceinline__ void scan8(unsigned long long gv, int kk,
                                      bool& anyset, bool& allp) {
    anyset = false; allp = true;
    #pragma unroll
    for (int i = 0; i < 8; ++i) {
        uint32_t b = (uint32_t)(gv >> (8 * i)) & 0xFFu;
        bool p = (b & 0xF0u) == 0xB0u;
        allp = allp && p;
        anyset = anyset || (p && (((b >> kk) & 1u) != 0u));
    }
}

// wide scan: 8 slots (8B stride), row byte is byte0 of each ull.
__device__ __forceinline__ void scan8w(const unsigned long long* g, int kk,
                                       bool& anyset, bool& allp) {
    anyset = false; allp = true;
    #pragma unroll
    for (int i = 0; i < 8; ++i) {
        uint32_t b = (uint32_t)(g[i] & 0xFFu);
        bool p = (b & 0xF0u) == 0xB0u;
        allp = allp && p;
        anyset = anyset || (p && (((b >> kk) & 1u) != 0u));
    }
}

// bfe-based decode (r27): values identical to the byte-wise decode.
__device__ __forceinline__ void decode_code(const uint4& c, float* xf, float* pf) {
    uint32_t cwd[4] = {c.x, c.y, c.z, c.w};
    #pragma unroll
    for (int j = 0; j < CPL; ++j) {
        xf[j] = (float)((cwd[j >> 2] >> ((j & 3) * 8)) & 1u);
        pf[j] = (float)((cwd[j >> 2] >> ((j & 3) * 8 + 1)) & 0x7Fu);
    }
}

// ---- fast bit-exact butterfly building blocks ----
typedef unsigned uint2ev __attribute__((ext_vector_type(2)));

__device__ __forceinline__ float pl32_sum(float v) {
    unsigned a = __builtin_bit_cast(unsigned, v);
    unsigned b = a;
#if __has_builtin(__builtin_amdgcn_permlane32_swap)
    uint2ev r = __builtin_amdgcn_permlane32_swap(a, b, false, false);
    a = r.x; b = r.y;
#else
    asm volatile("v_permlane32_swap_b32 %0, %1" : "+v"(a), "+v"(b));
#endif
    return __builtin_bit_cast(float, a) + __builtin_bit_cast(float, b);
}

__device__ __forceinline__ float pl16_sum(float v) {
    unsigned a = __builtin_bit_cast(unsigned, v);
    unsigned b = a;
#if __has_builtin(__builtin_amdgcn_permlane16_swap)
    uint2ev r = __builtin_amdgcn_permlane16_swap(a, b, false, false);
    a = r.x; b = r.y;
#else
    asm volatile("v_permlane16_swap_b32 %0, %1" : "+v"(a), "+v"(b));
#endif
    return __builtin_bit_cast(float, a) + __builtin_bit_cast(float, b);
}

template <int CTRL>
__device__ __forceinline__ float dpp_xor_sum(float v) {
    int xi = __builtin_bit_cast(int, v);
    int t = __builtin_amdgcn_update_dpp(xi, xi, CTRL, 0xF, 0xF, false);
    return v + __builtin_bit_cast(float, t);
}

// stage 4 (xor4 within 16-lane rows) in pure DPP (validated r23)
__device__ __forceinline__ float dpp_xor4_sum(float v) {
    int xi = __builtin_bit_cast(int, v);
    int t1 = __builtin_amdgcn_update_dpp(xi, xi, 0x124, 0xF, 0x5, false);
    int t2 = __builtin_amdgcn_update_dpp(t1, xi, 0x12C, 0xF, 0xA, false);
    return v + __builtin_bit_cast(float, t2);
}

// full 64-lane sum, pairing bit-identical to the validated xor butterfly
__device__ __forceinline__ float wave_sum(float v) {
    v = pl32_sum(v);                  // stage 32
    v = pl16_sum(v);                  // stage 16
    v = dpp_xor_sum<0x128>(v);        // stage 8
    v = dpp_xor4_sum(v);              // stage 4
    v = dpp_xor_sum<0x4E>(v);         // stage 2
    v = dpp_xor_sum<0xB1>(v);         // stage 1
    return v;
}

__device__ __forceinline__ int rfl(bool b) {
    return __builtin_amdgcn_readfirstlane((int)b);
}

// ======================= wide step (r28 verbatim) =======================
__device__ __forceinline__ void snn_step_w(
    int u, int row, int lane,
    const uint4* __restrict__ code4, uint8_t* __restrict__ slots,
    float (&wA)[CPL], float (&wB)[CPL],
    float (&xfc)[CPL], float (&pfc)[CPL],
    float (&xfn)[CPL], float (&pfn)[CPL],
    uint4& cwn, uint4& cwl,
    unsigned long long (&gcur)[8], unsigned long long (&gnxt)[8],
    float& memA, float& memB, bool& psA, bool& psB,
    int& p2, int& p3, int& hb_m1, int& hb_m2,
    bool& weq, uint32_t& myb)
{
    // ---- top-of-step: code load for u+2; selfdec from own history ----
    cwl = (u + 2 < T_STEPS) ? code4[(size_t)(u + 2) * 64 + lane]
                            : make_uint4(0u, 0u, 0u, 0u);
    const int kk = (p3 << 1) | p2;
    const bool selfdec = (u >= 2) && (((hb_m2 >> kk) & 1) != 0);
    const unsigned long long* gl =
        (const unsigned long long*)(slots + (size_t)(u >= 2 ? u - 2 : 0) * W_ROWBYTES);
    // gather for this step was PREFETCHED into gcur at end of step u-1.

    // ---- dots: world-B skipped while weq (wB dead, logically == wA) ----
    float dotA, dotB;
    if (rfl(weq)) {
        float dA = 0.0f;
        #pragma unroll
        for (int j = 0; j < CPL; ++j) dA += xfc[j] * wA[j];
        dotA = wave_sum(dA);
        dotB = dotA;                   // bitwise-identical
    } else {
        float dA = 0.0f, dB = 0.0f;
        #pragma unroll
        for (int j = 0; j < CPL; ++j) {
            dA += xfc[j] * wA[j];
            dB += xfc[j] * wB[j];
        }
        dotA = wave_sum(dA);
        dotB = wave_sum(dB);
    }

    // ---- pipelined decode of step u+1's codes ----
    decode_code(cwn, xfn, pfn);

    // ---- 4 hypotheses (verbatim) ----
    float sa = memA + dotA;
    float sb = memB + dotB;
    float m00 = fmaxf(sa, 0.0f), m01 = fmaxf(sa - PROHIB_F, 0.0f);
    float m10 = fmaxf(sb, 0.0f), m11 = fmaxf(sb - PROHIB_F, 0.0f);
    bool s00 = m00 >= VTHR_F, s01 = m01 >= VTHR_F;
    bool s10 = m10 >= VTHR_F, s11 = m11 >= VTHR_F;
    int hb = (s00 ? 1 : 0) | (s01 ? 2 : 0) | (s10 ? 4 : 0) | (s11 ? 8 : 0);

    // ---- publish own row's hb(u) (verbatim wide) ----
    if (lane == 0)
        __hip_atomic_store(&slots[(size_t)u * W_ROWBYTES + (size_t)row * 8],
                           (uint8_t)(0xB0u | (uint32_t)hb),
                           __ATOMIC_RELAXED, __HIP_MEMORY_SCOPE_AGENT);

    // ---- resolve P[u-1]: selfdec or prefetched gather + verbatim retry ----
    int bst = 0;
    if (u >= 2) {
        if (selfdec) {
            bst = 1;
        } else {
            bool anyset, allp;
            scan8w(gcur, kk, anyset, allp);
            if (__any((int)anyset)) { bst = 1; }
            else if (__all((int)allp)) { bst = 0; }
            else {
                for (;;) {
                    __builtin_amdgcn_s_sleep(1);       // backoff (rare path)
                    #pragma unroll
                    for (int i = 0; i < 8; ++i)
                        gcur[i] = __hip_atomic_load(&gl[8 * lane + i],
                                                    __ATOMIC_RELAXED,
                                                    __HIP_MEMORY_SCOPE_AGENT);
                    scan8w(gcur, kk, anyset, allp);
                    if (__any((int)anyset)) { bst = 1; break; }
                    if (__all((int)allp)) { bst = 0; break; }
                }
            }
        }
    }
    p3 = p2; p2 = bst;
    hb_m2 = hb_m1; hb_m1 = hb;

    // ---- collapse (verbatim) ----
    bool sprv = bst ? psB : psA;
    bool sc0  = bst ? s10 : s00;
    bool sc1  = bst ? s11 : s01;
    float mc0 = bst ? m10 : m00;
    float mc1 = bst ? m11 : m01;

    if (u >= 1) {
        int v = u - 1;
        if ((v & 63) == lane) myb |= (sprv ? 1u : 0u) << (v >> 6);
    }

    memA = sc0 ? 0.0f : mc0;
    memB = sc1 ? 0.0f : mc1;

    // ---- specialized weight updates (wave-uniform branches, bit-exact) ----
    const bool sc_eq = (sc0 == sc1);
    if (rfl(weq)) {
        if (rfl(sc_eq)) {
            if (rfl(sc0)) {                       // spike
                #pragma unroll
                for (int j = 0; j < CPL; ++j)
                    wA[j] = fminf(pfc[j] + wA[j], 127.0f);
            } else if (rfl(sprv)) {               // depression
                #pragma unroll
                for (int j = 0; j < CPL; ++j)
                    wA[j] = fmaxf(wA[j] - xfc[j], 0.0f);
            }                                     // else: unchanged
        } else {
            float s0f = sc0 ? 1.0f : 0.0f;
            float s1f = sc1 ? 1.0f : 0.0f;
            float d0f = (!sc0 && sprv) ? 1.0f : 0.0f;
            float d1f = (!sc1 && sprv) ? 1.0f : 0.0f;
            #pragma unroll
            for (int j = 0; j < CPL; ++j) {
                float base = wA[j];
                float ta = fminf(fmaf(s0f, pfc[j], base), 127.0f);
                wA[j] = fmaxf(fmaf(-d0f, xfc[j], ta), 0.0f);
                float tb = fminf(fmaf(s1f, pfc[j], base), 127.0f);
                wB[j] = fmaxf(fmaf(-d1f, xfc[j], tb), 0.0f);
            }
        }
    } else {
        if (rfl(sc_eq)) {
            if (rfl(bst != 0)) {
                if (rfl(sc0)) {
                    #pragma unroll
                    for (int j = 0; j < CPL; ++j)
                        wA[j] = fminf(pfc[j] + wB[j], 127.0f);
                } else if (rfl(sprv)) {
                    #pragma unroll
                    for (int j = 0; j < CPL; ++j)
                        wA[j] = fmaxf(wB[j] - xfc[j], 0.0f);
                } else {
                    #pragma unroll
                    for (int j = 0; j < CPL; ++j)
                        wA[j] = wB[j];
                }
            } else {
                if (rfl(sc0)) {
                    #pragma unroll
                    for (int j = 0; j < CPL; ++j)
                        wA[j] = fminf(pfc[j] + wA[j], 127.0f);
                } else if (rfl(sprv)) {
                    #pragma unroll
                    for (int j = 0; j < CPL; ++j)
                        wA[j] = fmaxf(wA[j] - xfc[j], 0.0f);
                }                                 // else: unchanged
            }
        } else {
            float s0f = sc0 ? 1.0f : 0.0f;
            float s1f = sc1 ? 1.0f : 0.0f;
            float d0f = (!sc0 && sprv) ? 1.0f : 0.0f;
            float d1f = (!sc1 && sprv) ? 1.0f : 0.0f;
            if (rfl(bst != 0)) {
                #pragma unroll
                for (int j = 0; j < CPL; ++j) {
                    float base = wB[j];
                    float ta = fminf(fmaf(s0f, pfc[j], base), 127.0f);
                    wA[j] = fmaxf(fmaf(-d0f, xfc[j], ta), 0.0f);
                    float tb = fminf(fmaf(s1f, pfc[j], base), 127.0f);
                    wB[j] = fmaxf(fmaf(-d1f, xfc[j], tb), 0.0f);
                }
            } else {
                #pragma unroll
                for (int j = 0; j < CPL; ++j) {
                    float base = wA[j];
                    float ta = fminf(fmaf(s0f, pfc[j], base), 127.0f);
                    wA[j] = fmaxf(fmaf(-d0f, xfc[j], ta), 0.0f);
                    float tb = fminf(fmaf(s1f, pfc[j], base), 127.0f);
                    wB[j] = fmaxf(fmaf(-d1f, xfc[j], tb), 0.0f);
                }
            }
        }
    }
    weq = sc_eq;
    psA = sc0; psB = sc1;

    // ---- distance-1 gated gather prefetch for step u+1 (verbatim r28) ----
    if (u + 1 < T_STEPS && u >= 1) {          // (u+1) >= 2
        const int kk2 = (p3 << 1) | p2;
        if (((hb_m2 >> kk2) & 1) == 0) {
            const unsigned long long* glp =
                (const unsigned long long*)(slots + (size_t)(u - 1) * W_ROWBYTES);
            #pragma unroll
            for (int i = 0; i < 8; ++i)
                gnxt[i] = __hip_atomic_load(&glp[8 * lane + i], __ATOMIC_RELAXED,
                                            __HIP_MEMORY_SCOPE_AGENT);
        }
    }
}

// 64 blocks x 512 threads: 8 waves/block = 2 waves/SIMD -> intra-SIMD
// stall-filling. Still exactly 512 co-resident waves (64 blocks <= 256 CUs).
__global__ __launch_bounds__(512, 1) void snn_kernel_w(const float* __restrict__ weight,
                                                       const uint8_t* __restrict__ code,
                                                       uint8_t* __restrict__ slots,
                                                       float* __restrict__ out) {
    const int tid  = threadIdx.x;
    const int wave = tid >> 6;
    const int lane = tid & 63;
    const int row  = blockIdx.x * 8 + wave;    // 512 autonomous waves, 64 CUs

    float wA[CPL], wB[CPL];
    #pragma unroll
    for (int j = 0; j < CPL; ++j) {
        int col = lane * CPL + j;
        float v = (col < CIN) ? weight[row * CIN + col] : 0.0f;
        wA[j] = v; wB[j] = v;
    }

    const uint4* code4 = (const uint4*)code;

    float xf0[CPL], pf0[CPL], xf1[CPL], pf1[CPL];
    {
        uint4 c0 = code4[lane];
        decode_code(c0, xf0, pf0);
    }
    uint4 cwA = code4[64 + lane];
    uint4 cwB = make_uint4(0u, 0u, 0u, 0u);

    unsigned long long gA[8], gB[8];
    #pragma unroll
    for (int i = 0; i < 8; ++i) { gA[i] = 0xB0B0B0B0B0B0B0B0ull; gB[i] = gA[i]; }

    float memA = 0.0f, memB = 0.0f;
    bool  psA = true, psB = true;          // spike(-1)=true quirk
    int p2 = 0, p3 = 0;
    int hb_m1 = 0, hb_m2 = 0;
    bool weq = true;                       // wA==wB at start
    uint32_t myb = 0u;

    for (int u = 0; u < T_STEPS; u += 2) {
        snn_step_w(u,     row, lane, code4, slots, wA, wB,
                   xf0, pf0, xf1, pf1, cwA, cwB, gA, gB,
                   memA, memB, psA, psB, p2, p3, hb_m1, hb_m2, weq, myb);
        snn_step_w(u + 1, row, lane, code4, slots, wA, wB,
                   xf1, pf1, xf0, pf0, cwB, cwA, gB, gA,
                   memA, memB, psA, psB, p2, p3, hb_m1, hb_m2, weq, myb);
    }

    // ---- epilogue (verbatim wide) ----
    {
        const int kk = (p3 << 1) | p2;
        int cst;
        if (((hb_m2 >> kk) & 1) != 0) {
            cst = 1;
        } else {
            const unsigned long long* gl2 =
                (const unsigned long long*)(slots + (size_t)(T_STEPS - 2) * W_ROWBYTES);
            unsigned long long g2[8];
            for (;;) {
                #pragma unroll
                for (int i = 0; i < 8; ++i)
                    g2[i] = __hip_atomic_load(&gl2[8 * lane + i],
                                              __ATOMIC_RELAXED,
                                              __HIP_MEMORY_SCOPE_AGENT);
                bool anyset, allp;
                scan8w(g2, kk, anyset, allp);
                if (__any((int)anyset)) { cst = 1; break; }
                if (__all((int)allp)) { cst = 0; break; }
                __builtin_amdgcn_s_sleep(1);
            }
        }
        bool sr = cst ? psB : psA;
        {
            int v = T_STEPS - 1;
            if ((v & 63) == lane) myb |= (sr ? 1u : 0u) << (v >> 6);
        }
        #pragma unroll
        for (int b = 0; b < 16; ++b) {
            int s = b * 64 + lane;
            if (s < T_STEPS)
                out[(size_t)s * COUT + row] = (float)((myb >> b) & 1u);
        }
    }
}

// ======================= narrow fallback (proven r24 narrow) =======================
__device__ __forceinline__ void snn_step_n(
    int u, int row, int lane,
    const uint4* __restrict__ code4, uint8_t* __restrict__ slots,
    float (&wA)[CPL], float (&wB)[CPL],
    float (&xfc)[CPL], float (&pfc)[CPL],
    float (&xfn)[CPL], float (&pfn)[CPL],
    uint4& cwn, uint4& cwl,
    float& memA, float& memB, bool& psA, bool& psB,
    int& p2, int& p3, int& hb_m1, int& hb_m2,
    uint32_t& myb)
{
    cwl = (u + 2 < T_STEPS) ? code4[(size_t)(u + 2) * 64 + lane]
                            : make_uint4(0u, 0u, 0u, 0u);
    const int kk = (p3 << 1) | p2;
    const bool selfdec = (u >= 2) && (((hb_m2 >> kk) & 1) != 0);
    const unsigned long long* gl =
        (const unsigned long long*)(slots + (size_t)(u >= 2 ? u - 2 : 0) * N_NROW);
    unsigned long long gv = 0xB0B0B0B0B0B0B0B0ull;
    if (u >= 2 && !selfdec)
        gv = __hip_atomic_load(&gl[lane], __ATOMIC_RELAXED,
                               __HIP_MEMORY_SCOPE_AGENT);

    float dA = 0.0f, dB = 0.0f;
    #pragma unroll
    for (int j = 0; j < CPL; ++j) { dA += xfc[j] * wA[j]; dB += xfc[j] * wB[j]; }
    float dotA = wave_sum(dA);
    float dotB = wave_sum(dB);

    decode_code(cwn, xfn, pfn);

    float sa = memA + dotA;
    float sb = memB + dotB;
    float m00 = fmaxf(sa, 0.0f), m01 = fmaxf(sa - PROHIB_F, 0.0f);
    float m10 = fmaxf(sb, 0.0f), m11 = fmaxf(sb - PROHIB_F, 0.0f);
    bool s00 = m00 >= VTHR_F, s01 = m01 >= VTHR_F;
    bool s10 = m10 >= VTHR_F, s11 = m11 >= VTHR_F;
    int hb = (s00 ? 1 : 0) | (s01 ? 2 : 0) | (s10 ? 4 : 0) | (s11 ? 8 : 0);

    if (lane == 0)
        __hip_atomic_store(&slots[(size_t)u * N_NROW + row],
                           (uint8_t)(0xB0u | (uint32_t)hb),
                           __ATOMIC_RELAXED, __HIP_MEMORY_SCOPE_AGENT);

    int bst = 0;
    if (u >= 2) {
        if (selfdec) {
            bst = 1;
        } else {
            for (;;) {
                bool anyset, allp;
                scan8(gv, kk, anyset, allp);
                if (__any((int)anyset)) { bst = 1; break; }
                if (__all((int)allp)) { bst = 0; break; }
                __builtin_amdgcn_s_sleep(1);
                gv = __hip_atomic_load(&gl[lane], __ATOMIC_RELAXED,
                                       __HIP_MEMORY_SCOPE_AGENT);
            }
        }
    }
    p3 = p2; p2 = bst;
    hb_m2 = hb_m1; hb_m1 = hb;

    bool sprv = bst ? psB : psA;
    bool sc0  = bst ? s10 : s00;
    bool sc1  = bst ? s11 : s01;
    float mc0 = bst ? m10 : m00;
    float mc1 = bst ? m11 : m01;

    if (u >= 1) {
        int v = u - 1;
        if ((v & 63) == lane) myb |= (sprv ? 1u : 0u) << (v >> 6);
    }

    memA = sc0 ? 0.0f : mc0;
    memB = sc1 ? 0.0f : mc1;

    float s0f = sc0 ? 1.0f : 0.0f;
    float s1f = sc1 ? 1.0f : 0.0f;
    float d0f = (!sc0 && sprv) ? 1.0f : 0.0f;
    float d1f = (!sc1 && sprv) ? 1.0f : 0.0f;
    #pragma unroll
    for (int j = 0; j < CPL; ++j) {
        float base = bst ? wB[j] : wA[j];
        float ta = fminf(fmaf(s0f, pfc[j], base), 127.0f);
        wA[j] = fmaxf(fmaf(-d0f, xfc[j], ta), 0.0f);
        float tb = fminf(fmaf(s1f, pfc[j], base), 127.0f);
        wB[j] = fmaxf(fmaf(-d1f, xfc[j], tb), 0.0f);
    }
    psA = sc0; psB = sc1;
}

__global__ __launch_bounds__(128, 1) void snn_kernel_n(const float* __restrict__ weight,
                                                       const uint8_t* __restrict__ code,
                                                       uint8_t* __restrict__ slots,
                                                       float* __restrict__ out) {
    const int tid  = threadIdx.x;
    const int wave = tid >> 6;
    const int lane = tid & 63;
    const int row  = blockIdx.x * 2 + wave;

    float wA[CPL], wB[CPL];
    #pragma unroll
    for (int j = 0; j < CPL; ++j) {
        int col = lane * CPL + j;
        float v = (col < CIN) ? weight[row * CIN + col] : 0.0f;
        wA[j] = v; wB[j] = v;
    }

    const uint4* code4 = (const uint4*)code;
    float xf0[CPL], pf0[CPL], xf1[CPL], pf1[CPL];
    {
        uint4 c0 = code4[lane];
        decode_code(c0, xf0, pf0);
    }
    uint4 cwA = code4[64 + lane];
    uint4 cwB = make_uint4(0u, 0u, 0u, 0u);

    float memA = 0.0f, memB = 0.0f;
    bool  psA = true, psB = true;
    int p2 = 0, p3 = 0;
    int hb_m1 = 0, hb_m2 = 0;
    uint32_t myb = 0u;

    for (int u = 0; u < T_STEPS; u += 2) {
        snn_step_n(u,     row, lane, code4, slots, wA, wB,
                   xf0, pf0, xf1, pf1, cwA, cwB,
                   memA, memB, psA, psB, p2, p3, hb_m1, hb_m2, myb);
        snn_step_n(u + 1, row, lane, code4, slots, wA, wB,
                   xf1, pf1, xf0, pf0, cwB, cwA,
                   memA, memB, psA, psB, p2, p3, hb_m1, hb_m2, myb);
    }

    {
        const int kk = (p3 << 1) | p2;
        int cst;
        if (((hb_m2 >> kk) & 1) != 0) {
            cst = 1;
        } else {
            const unsigned long long* gl2 =
                (const unsigned long long*)(slots + (size_t)(T_STEPS - 2) * N_NROW);
            unsigned long long gv2;
            for (;;) {
                gv2 = __hip_atomic_load(&gl2[lane], __ATOMIC_RELAXED,
                                        __HIP_MEMORY_SCOPE_AGENT);
                bool anyset, allp;
                scan8(gv2, kk, anyset, allp);
                if (__any((int)anyset)) { cst = 1; break; }
                if (__all((int)allp)) { cst = 0; break; }
                __builtin_amdgcn_s_sleep(1);
            }
        }
        bool sr = cst ? psB : psA;
        {
            int v = T_STEPS - 1;
            if ((v & 63) == lane) myb |= (sr ? 1u : 0u) << (v >> 6);
        }
        #pragma unroll
        for (int b = 0; b < 16; ++b) {
            int s = b * 64 + lane;
            if (s < T_STEPS)
                out[(size_t)s * COUT + row] = (float)((myb >> b) & 1u);
        }
    }
}

extern "C" void kernel_launch(void* const* d_in, const int* in_sizes, int n_in,
                              void* d_out, int out_size, void* d_ws, size_t ws_size,
                              hipStream_t stream) {
    const int*   x      = (const int*)d_in[0];     // (T,1,CIN) int32
    const float* weight = (const float*)d_in[1];   // (COUT,CIN) f32
    float* out = (float*)d_out;                    // (T,1,COUT) f32

    int prep_threads = T_STEPS * 64;
    int prep_blocks = (prep_threads + 255) / 256;
    if (ws_size >= W_TOTAL) {
        uint8_t* slots = (uint8_t*)d_ws;
        uint8_t* code  = (uint8_t*)d_ws + W_CODE_OFFSET;
        prep_kernel<true><<<prep_blocks, 256, 0, stream>>>(x, code, slots);
        snn_kernel_w<<<64, 512, 0, stream>>>(weight, code, slots, out);
    } else {
        uint8_t* slots = (uint8_t*)d_ws;
        uint8_t* code  = (uint8_t*)d_ws + N_CODE_OFFSET;
        prep_kernel<false><<<prep_blocks, 256, 0, stream>>>(x, code, slots);
        snn_kernel_n<<<256, 128, 0, stream>>>(weight, code, slots, out);
    }
}

// Round 14
// 784.788 us; speedup vs baseline: 1.2732x; 1.1753x over previous
//
#include <hip/hip_runtime.h>
#include <stdint.h>

// Net_11587821765063: sequential SNN scan, T=1000 steps.
// Output = spike_out (T,1,COUT) float32 only.
//
// Round 33 (session r13): CHAMPION RESTORATION — r28 verbatim (734us
// dispatch, measured twice across sessions). r12's 2-waves/SIMD geometry
// regressed (869us: correlated stalls + issue-port contention), closing the
// last untested lever. Final pace model over 10 kernels:
//   pace ~= 2*issue + ~1000cy,
// residual invariant to slack depth (r25/r31), publish semantics (r30),
// prefetch distance (r28), memory source (r29), occupancy (r12) ->
// intra-step serial latency (dep chains ~200cy, ~10 branch refills ~300cy,
// waitcnt/issue overheads) inherent to the algorithm-protocol structure.
// Champion structure: 256 blocks x 128 threads (512 autonomous 1-row waves,
// all 256 CUs), wide 8B-stride slots, publish 0xB0|hb byte, scan8w + retry
// + selfdec, distance-1 GATED gather prefetch into swapped register pairs,
// weq world-merging, wave-uniform specialized updates, bfe decode.
// Narrow-ws fallback: proven r24 narrow path verbatim.

#define T_STEPS 1000
#define CIN     784
#define COUT    512
#define CPL     13            // columns per lane (64*13 = 832 >= 784)
#define VTHR_F   12500.0f
#define PROHIB_F 11250.0f

// narrow (proven) layout
#define N_NROW        512                     // 1B per row per step
#define N_CODE_OFFSET 524288                  // 512 KiB >= 512000 B of slots
// wide layout (proven r24/r28): 8B per row per step
#define W_ROWBYTES    4096                    // 512 rows * 8B stride
#define W_CODE_OFFSET 4194304                 // 4 MiB >= 4,096,000 B of slots
#define CODE_BYTES    (T_STEPS * 64 * 16)     // 1,024,000 B
#define W_TOTAL       ((size_t)W_CODE_OFFSET + (size_t)CODE_BYTES)

// ---- prep: zero slots and pack per-(t,lane) 16-byte code slot:
// byte j (j<13) encodes col = lane*13+j: bit0 = x[t][col], bits[2:1] = p.
template <bool WIDE>
__global__ __launch_bounds__(256) void prep_kernel(const int* __restrict__ x,
                                                   uint8_t* __restrict__ code,
                                                   uint8_t* __restrict__ slots) {
    int gid = blockIdx.x * blockDim.x + threadIdx.x;   // one per (t, lane)
    if (gid >= T_STEPS * 64) return;
    if constexpr (WIDE) {
        uint4 z = make_uint4(0u, 0u, 0u, 0u);
        uint4* s4 = (uint4*)slots;                      // 64000 x 64B = 4.096MB
        #pragma unroll
        for (int k = 0; k < 4; ++k) s4[(size_t)gid * 4 + k] = z;
    } else {
        ((uint2*)slots)[gid] = make_uint2(0u, 0u);      // 64000 x 8B
    }
    int t = gid >> 6;
    int lane = gid & 63;
    uint32_t wds[4] = {0u, 0u, 0u, 0u};
    #pragma unroll
    for (int j = 0; j < CPL; ++j) {
        int col = lane * CPL + j;
        uint32_t b = 0u;
        if (col < CIN) {
            int xc = x[t * CIN + col];
            int xp = (t > 0) ? x[(t - 1) * CIN + col] : 0;
            int p = xc ? 2 : ((t == 0) ? 1 : (xp ? 1 : 0));
            b = (uint32_t)((xc & 1) | (p << 1));
        }
        wds[j >> 2] |= b << ((j & 3) * 8);
    }
    ((uint4*)code)[gid] = make_uint4(wds[0], wds[1], wds[2], wds[3]);
}

// narrow scan: 8 row-bytes in one ull
__device__ __forceinline__ void scan8(unsigned long long gv, int kk,
                                      bool& anyset, bool& allp) {
    anyset = false; allp = true;
    #pragma unroll
    for (int i = 0; i < 8; ++i) {
        uint32_t b = (uint32_t)(gv >> (8 * i)) & 0xFFu;
        bool p = (b & 0xF0u) == 0xB0u;
        allp = allp && p;
        anyset = anyset || (p && (((b >> kk) & 1u) != 0u));
    }
}

// wide scan: 8 slots (8B stride), row byte is byte0 of each ull.
__device__ __forceinline__ void scan8w(const unsigned long long* g, int kk,
                                       bool& anyset, bool& allp) {
    anyset = false; allp = true;
    #pragma unroll
    for (int i = 0; i < 8; ++i) {
        uint32_t b = (uint32_t)(g[i] & 0xFFu);
        bool p = (b & 0xF0u) == 0xB0u;
        allp = allp && p;
        anyset = anyset || (p && (((b >> kk) & 1u) != 0u));
    }
}

// bfe-based decode (r27): values identical to the byte-wise decode.
__device__ __forceinline__ void decode_code(const uint4& c, float* xf, float* pf) {
    uint32_t cwd[4] = {c.x, c.y, c.z, c.w};
    #pragma unroll
    for (int j = 0; j < CPL; ++j) {
        xf[j] = (float)((cwd[j >> 2] >> ((j & 3) * 8)) & 1u);
        pf[j] = (float)((cwd[j >> 2] >> ((j & 3) * 8 + 1)) & 0x7Fu);
    }
}

// ---- fast bit-exact butterfly building blocks ----
typedef unsigned uint2ev __attribute__((ext_vector_type(2)));

__device__ __forceinline__ float pl32_sum(float v) {
    unsigned a = __builtin_bit_cast(unsigned, v);
    unsigned b = a;
#if __has_builtin(__builtin_amdgcn_permlane32_swap)
    uint2ev r = __builtin_amdgcn_permlane32_swap(a, b, false, false);
    a = r.x; b = r.y;
#else
    asm volatile("v_permlane32_swap_b32 %0, %1" : "+v"(a), "+v"(b));
#endif
    return __builtin_bit_cast(float, a) + __builtin_bit_cast(float, b);
}

__device__ __forceinline__ float pl16_sum(float v) {
    unsigned a = __builtin_bit_cast(unsigned, v);
    unsigned b = a;
#if __has_builtin(__builtin_amdgcn_permlane16_swap)
    uint2ev r = __builtin_amdgcn_permlane16_swap(a, b, false, false);
    a = r.x; b = r.y;
#else
    asm volatile("v_permlane16_swap_b32 %0, %1" : "+v"(a), "+v"(b));
#endif
    return __builtin_bit_cast(float, a) + __builtin_bit_cast(float, b);
}

template <int CTRL>
__device__ __forceinline__ float dpp_xor_sum(float v) {
    int xi = __builtin_bit_cast(int, v);
    int t = __builtin_amdgcn_update_dpp(xi, xi, CTRL, 0xF, 0xF, false);
    return v + __builtin_bit_cast(float, t);
}

// stage 4 (xor4 within 16-lane rows) in pure DPP (validated r23)
__device__ __forceinline__ float dpp_xor4_sum(float v) {
    int xi = __builtin_bit_cast(int, v);
    int t1 = __builtin_amdgcn_update_dpp(xi, xi, 0x124, 0xF, 0x5, false);
    int t2 = __builtin_amdgcn_update_dpp(t1, xi, 0x12C, 0xF, 0xA, false);
    return v + __builtin_bit_cast(float, t2);
}

// full 64-lane sum, pairing bit-identical to the validated xor butterfly
__device__ __forceinline__ float wave_sum(float v) {
    v = pl32_sum(v);                  // stage 32
    v = pl16_sum(v);                  // stage 16
    v = dpp_xor_sum<0x128>(v);        // stage 8
    v = dpp_xor4_sum(v);              // stage 4
    v = dpp_xor_sum<0x4E>(v);         // stage 2
    v = dpp_xor_sum<0xB1>(v);         // stage 1
    return v;
}

__device__ __forceinline__ int rfl(bool b) {
    return __builtin_amdgcn_readfirstlane((int)b);
}

// ======================= wide step (r28 verbatim) =======================
__device__ __forceinline__ void snn_step_w(
    int u, int row, int lane,
    const uint4* __restrict__ code4, uint8_t* __restrict__ slots,
    float (&wA)[CPL], float (&wB)[CPL],
    float (&xfc)[CPL], float (&pfc)[CPL],
    float (&xfn)[CPL], float (&pfn)[CPL],
    uint4& cwn, uint4& cwl,
    unsigned long long (&gcur)[8], unsigned long long (&gnxt)[8],
    float& memA, float& memB, bool& psA, bool& psB,
    int& p2, int& p3, int& hb_m1, int& hb_m2,
    bool& weq, uint32_t& myb)
{
    // ---- top-of-step: code load for u+2; selfdec from own history ----
    cwl = (u + 2 < T_STEPS) ? code4[(size_t)(u + 2) * 64 + lane]
                            : make_uint4(0u, 0u, 0u, 0u);
    const int kk = (p3 << 1) | p2;
    const bool selfdec = (u >= 2) && (((hb_m2 >> kk) & 1) != 0);
    const unsigned long long* gl =
        (const unsigned long long*)(slots + (size_t)(u >= 2 ? u - 2 : 0) * W_ROWBYTES);
    // gather for this step was PREFETCHED into gcur at end of step u-1.

    // ---- dots: world-B skipped while weq (wB dead, logically == wA) ----
    float dotA, dotB;
    if (rfl(weq)) {
        float dA = 0.0f;
        #pragma unroll
        for (int j = 0; j < CPL; ++j) dA += xfc[j] * wA[j];
        dotA = wave_sum(dA);
        dotB = dotA;                   // bitwise-identical
    } else {
        float dA = 0.0f, dB = 0.0f;
        #pragma unroll
        for (int j = 0; j < CPL; ++j) {
            dA += xfc[j] * wA[j];
            dB += xfc[j] * wB[j];
        }
        dotA = wave_sum(dA);
        dotB = wave_sum(dB);
    }

    // ---- pipelined decode of step u+1's codes ----
    decode_code(cwn, xfn, pfn);

    // ---- 4 hypotheses (verbatim) ----
    float sa = memA + dotA;
    float sb = memB + dotB;
    float m00 = fmaxf(sa, 0.0f), m01 = fmaxf(sa - PROHIB_F, 0.0f);
    float m10 = fmaxf(sb, 0.0f), m11 = fmaxf(sb - PROHIB_F, 0.0f);
    bool s00 = m00 >= VTHR_F, s01 = m01 >= VTHR_F;
    bool s10 = m10 >= VTHR_F, s11 = m11 >= VTHR_F;
    int hb = (s00 ? 1 : 0) | (s01 ? 2 : 0) | (s10 ? 4 : 0) | (s11 ? 8 : 0);

    // ---- publish own row's hb(u) (verbatim wide) ----
    if (lane == 0)
        __hip_atomic_store(&slots[(size_t)u * W_ROWBYTES + (size_t)row * 8],
                           (uint8_t)(0xB0u | (uint32_t)hb),
                           __ATOMIC_RELAXED, __HIP_MEMORY_SCOPE_AGENT);

    // ---- resolve P[u-1]: selfdec or prefetched gather + verbatim retry ----
    int bst = 0;
    if (u >= 2) {
        if (selfdec) {
            bst = 1;
        } else {
            bool anyset, allp;
            scan8w(gcur, kk, anyset, allp);
            if (__any((int)anyset)) { bst = 1; }
            else if (__all((int)allp)) { bst = 0; }
            else {
                for (;;) {
                    __builtin_amdgcn_s_sleep(1);       // backoff (rare path)
                    #pragma unroll
                    for (int i = 0; i < 8; ++i)
                        gcur[i] = __hip_atomic_load(&gl[8 * lane + i],
                                                    __ATOMIC_RELAXED,
                                                    __HIP_MEMORY_SCOPE_AGENT);
                    scan8w(gcur, kk, anyset, allp);
                    if (__any((int)anyset)) { bst = 1; break; }
                    if (__all((int)allp)) { bst = 0; break; }
                }
            }
        }
    }
    p3 = p2; p2 = bst;
    hb_m2 = hb_m1; hb_m1 = hb;

    // ---- collapse (verbatim) ----
    bool sprv = bst ? psB : psA;
    bool sc0  = bst ? s10 : s00;
    bool sc1  = bst ? s11 : s01;
    float mc0 = bst ? m10 : m00;
    float mc1 = bst ? m11 : m01;

    if (u >= 1) {
        int v = u - 1;
        if ((v & 63) == lane) myb |= (sprv ? 1u : 0u) << (v >> 6);
    }

    memA = sc0 ? 0.0f : mc0;
    memB = sc1 ? 0.0f : mc1;

    // ---- specialized weight updates (wave-uniform branches, bit-exact) ----
    const bool sc_eq = (sc0 == sc1);
    if (rfl(weq)) {
        if (rfl(sc_eq)) {
            if (rfl(sc0)) {                       // spike
                #pragma unroll
                for (int j = 0; j < CPL; ++j)
                    wA[j] = fminf(pfc[j] + wA[j], 127.0f);
            } else if (rfl(sprv)) {               // depression
                #pragma unroll
                for (int j = 0; j < CPL; ++j)
                    wA[j] = fmaxf(wA[j] - xfc[j], 0.0f);
            }                                     // else: unchanged
        } else {
            float s0f = sc0 ? 1.0f : 0.0f;
            float s1f = sc1 ? 1.0f : 0.0f;
            float d0f = (!sc0 && sprv) ? 1.0f : 0.0f;
            float d1f = (!sc1 && sprv) ? 1.0f : 0.0f;
            #pragma unroll
            for (int j = 0; j < CPL; ++j) {
                float base = wA[j];
                float ta = fminf(fmaf(s0f, pfc[j], base), 127.0f);
                wA[j] = fmaxf(fmaf(-d0f, xfc[j], ta), 0.0f);
                float tb = fminf(fmaf(s1f, pfc[j], base), 127.0f);
                wB[j] = fmaxf(fmaf(-d1f, xfc[j], tb), 0.0f);
            }
        }
    } else {
        if (rfl(sc_eq)) {
            if (rfl(bst != 0)) {
                if (rfl(sc0)) {
                    #pragma unroll
                    for (int j = 0; j < CPL; ++j)
                        wA[j] = fminf(pfc[j] + wB[j], 127.0f);
                } else if (rfl(sprv)) {
                    #pragma unroll
                    for (int j = 0; j < CPL; ++j)
                        wA[j] = fmaxf(wB[j] - xfc[j], 0.0f);
                } else {
                    #pragma unroll
                    for (int j = 0; j < CPL; ++j)
                        wA[j] = wB[j];
                }
            } else {
                if (rfl(sc0)) {
                    #pragma unroll
                    for (int j = 0; j < CPL; ++j)
                        wA[j] = fminf(pfc[j] + wA[j], 127.0f);
                } else if (rfl(sprv)) {
                    #pragma unroll
                    for (int j = 0; j < CPL; ++j)
                        wA[j] = fmaxf(wA[j] - xfc[j], 0.0f);
                }                                 // else: unchanged
            }
        } else {
            float s0f = sc0 ? 1.0f : 0.0f;
            float s1f = sc1 ? 1.0f : 0.0f;
            float d0f = (!sc0 && sprv) ? 1.0f : 0.0f;
            float d1f = (!sc1 && sprv) ? 1.0f : 0.0f;
            if (rfl(bst != 0)) {
                #pragma unroll
                for (int j = 0; j < CPL; ++j) {
                    float base = wB[j];
                    float ta = fminf(fmaf(s0f, pfc[j], base), 127.0f);
                    wA[j] = fmaxf(fmaf(-d0f, xfc[j], ta), 0.0f);
                    float tb = fminf(fmaf(s1f, pfc[j], base), 127.0f);
                    wB[j] = fmaxf(fmaf(-d1f, xfc[j], tb), 0.0f);
                }
            } else {
                #pragma unroll
                for (int j = 0; j < CPL; ++j) {
                    float base = wA[j];
                    float ta = fminf(fmaf(s0f, pfc[j], base), 127.0f);
                    wA[j] = fmaxf(fmaf(-d0f, xfc[j], ta), 0.0f);
                    float tb = fminf(fmaf(s1f, pfc[j], base), 127.0f);
                    wB[j] = fmaxf(fmaf(-d1f, xfc[j], tb), 0.0f);
                }
            }
        }
    }
    weq = sc_eq;
    psA = sc0; psB = sc1;

    // ---- distance-1 gated gather prefetch for step u+1 (verbatim r28) ----
    if (u + 1 < T_STEPS && u >= 1) {          // (u+1) >= 2
        const int kk2 = (p3 << 1) | p2;
        if (((hb_m2 >> kk2) & 1) == 0) {
            const unsigned long long* glp =
                (const unsigned long long*)(slots + (size_t)(u - 1) * W_ROWBYTES);
            #pragma unroll
            for (int i = 0; i < 8; ++i)
                gnxt[i] = __hip_atomic_load(&glp[8 * lane + i], __ATOMIC_RELAXED,
                                            __HIP_MEMORY_SCOPE_AGENT);
        }
    }
}

__global__ __launch_bounds__(128, 1) void snn_kernel_w(const float* __restrict__ weight,
                                                       const uint8_t* __restrict__ code,
                                                       uint8_t* __restrict__ slots,
                                                       float* __restrict__ out) {
    const int tid  = threadIdx.x;
    const int wave = tid >> 6;
    const int lane = tid & 63;
    const int row  = blockIdx.x * 2 + wave;    // 512 autonomous waves, 256 CUs

    float wA[CPL], wB[CPL];
    #pragma unroll
    for (int j = 0; j < CPL; ++j) {
        int col = lane * CPL + j;
        float v = (col < CIN) ? weight[row * CIN + col] : 0.0f;
        wA[j] = v; wB[j] = v;
    }

    const uint4* code4 = (const uint4*)code;

    float xf0[CPL], pf0[CPL], xf1[CPL], pf1[CPL];
    {
        uint4 c0 = code4[lane];
        decode_code(c0, xf0, pf0);
    }
    uint4 cwA = code4[64 + lane];
    uint4 cwB = make_uint4(0u, 0u, 0u, 0u);

    unsigned long long gA[8], gB[8];
    #pragma unroll
    for (int i = 0; i < 8; ++i) { gA[i] = 0xB0B0B0B0B0B0B0B0ull; gB[i] = gA[i]; }

    float memA = 0.0f, memB = 0.0f;
    bool  psA = true, psB = true;          // spike(-1)=true quirk
    int p2 = 0, p3 = 0;
    int hb_m1 = 0, hb_m2 = 0;
    bool weq = true;                       // wA==wB at start
    uint32_t myb = 0u;

    for (int u = 0; u < T_STEPS; u += 2) {
        snn_step_w(u,     row, lane, code4, slots, wA, wB,
                   xf0, pf0, xf1, pf1, cwA, cwB, gA, gB,
                   memA, memB, psA, psB, p2, p3, hb_m1, hb_m2, weq, myb);
        snn_step_w(u + 1, row, lane, code4, slots, wA, wB,
                   xf1, pf1, xf0, pf0, cwB, cwA, gB, gA,
                   memA, memB, psA, psB, p2, p3, hb_m1, hb_m2, weq, myb);
    }

    // ---- epilogue (verbatim wide) ----
    {
        const int kk = (p3 << 1) | p2;
        int cst;
        if (((hb_m2 >> kk) & 1) != 0) {
            cst = 1;
        } else {
            const unsigned long long* gl2 =
                (const unsigned long long*)(slots + (size_t)(T_STEPS - 2) * W_ROWBYTES);
            unsigned long long g2[8];
            for (;;) {
                #pragma unroll
                for (int i = 0; i < 8; ++i)
                    g2[i] = __hip_atomic_load(&gl2[8 * lane + i],
                                              __ATOMIC_RELAXED,
                                              __HIP_MEMORY_SCOPE_AGENT);
                bool anyset, allp;
                scan8w(g2, kk, anyset, allp);
                if (__any((int)anyset)) { cst = 1; break; }
                if (__all((int)allp)) { cst = 0; break; }
                __builtin_amdgcn_s_sleep(1);
            }
        }
        bool sr = cst ? psB : psA;
        {
            int v = T_STEPS - 1;
            if ((v & 63) == lane) myb |= (sr ? 1u : 0u) << (v >> 6);
        }
        #pragma unroll
        for (int b = 0; b < 16; ++b) {
            int s = b * 64 + lane;
            if (s < T_STEPS)
                out[(size_t)s * COUT + row] = (float)((myb >> b) & 1u);
        }
    }
}

// ======================= narrow fallback (proven r24 narrow) =======================
__device__ __forceinline__ void snn_step_n(
    int u, int row, int lane,
    const uint4* __restrict__ code4, uint8_t* __restrict__ slots,
    float (&wA)[CPL], float (&wB)[CPL],
    float (&xfc)[CPL], float (&pfc)[CPL],
    float (&xfn)[CPL], float (&pfn)[CPL],
    uint4& cwn, uint4& cwl,
    float& memA, float& memB, bool& psA, bool& psB,
    int& p2, int& p3, int& hb_m1, int& hb_m2,
    uint32_t& myb)
{
    cwl = (u + 2 < T_STEPS) ? code4[(size_t)(u + 2) * 64 + lane]
                            : make_uint4(0u, 0u, 0u, 0u);
    const int kk = (p3 << 1) | p2;
    const bool selfdec = (u >= 2) && (((hb_m2 >> kk) & 1) != 0);
    const unsigned long long* gl =
        (const unsigned long long*)(slots + (size_t)(u >= 2 ? u - 2 : 0) * N_NROW);
    unsigned long long gv = 0xB0B0B0B0B0B0B0B0ull;
    if (u >= 2 && !selfdec)
        gv = __hip_atomic_load(&gl[lane], __ATOMIC_RELAXED,
                               __HIP_MEMORY_SCOPE_AGENT);

    float dA = 0.0f, dB = 0.0f;
    #pragma unroll
    for (int j = 0; j < CPL; ++j) { dA += xfc[j] * wA[j]; dB += xfc[j] * wB[j]; }
    float dotA = wave_sum(dA);
    float dotB = wave_sum(dB);

    decode_code(cwn, xfn, pfn);

    float sa = memA + dotA;
    float sb = memB + dotB;
    float m00 = fmaxf(sa, 0.0f), m01 = fmaxf(sa - PROHIB_F, 0.0f);
    float m10 = fmaxf(sb, 0.0f), m11 = fmaxf(sb - PROHIB_F, 0.0f);
    bool s00 = m00 >= VTHR_F, s01 = m01 >= VTHR_F;
    bool s10 = m10 >= VTHR_F, s11 = m11 >= VTHR_F;
    int hb = (s00 ? 1 : 0) | (s01 ? 2 : 0) | (s10 ? 4 : 0) | (s11 ? 8 : 0);

    if (lane == 0)
        __hip_atomic_store(&slots[(size_t)u * N_NROW + row],
                           (uint8_t)(0xB0u | (uint32_t)hb),
                           __ATOMIC_RELAXED, __HIP_MEMORY_SCOPE_AGENT);

    int bst = 0;
    if (u >= 2) {
        if (selfdec) {
            bst = 1;
        } else {
            for (;;) {
                bool anyset, allp;
                scan8(gv, kk, anyset, allp);
                if (__any((int)anyset)) { bst = 1; break; }
                if (__all((int)allp)) { bst = 0; break; }
                __builtin_amdgcn_s_sleep(1);
                gv = __hip_atomic_load(&gl[lane], __ATOMIC_RELAXED,
                                       __HIP_MEMORY_SCOPE_AGENT);
            }
        }
    }
    p3 = p2; p2 = bst;
    hb_m2 = hb_m1; hb_m1 = hb;

    bool sprv = bst ? psB : psA;
    bool sc0  = bst ? s10 : s00;
    bool sc1  = bst ? s11 : s01;
    float mc0 = bst ? m10 : m00;
    float mc1 = bst ? m11 : m01;

    if (u >= 1) {
        int v = u - 1;
        if ((v & 63) == lane) myb |= (sprv ? 1u : 0u) << (v >> 6);
    }

    memA = sc0 ? 0.0f : mc0;
    memB = sc1 ? 0.0f : mc1;

    float s0f = sc0 ? 1.0f : 0.0f;
    float s1f = sc1 ? 1.0f : 0.0f;
    float d0f = (!sc0 && sprv) ? 1.0f : 0.0f;
    float d1f = (!sc1 && sprv) ? 1.0f : 0.0f;
    #pragma unroll
    for (int j = 0; j < CPL; ++j) {
        float base = bst ? wB[j] : wA[j];
        float ta = fminf(fmaf(s0f, pfc[j], base), 127.0f);
        wA[j] = fmaxf(fmaf(-d0f, xfc[j], ta), 0.0f);
        float tb = fminf(fmaf(s1f, pfc[j], base), 127.0f);
        wB[j] = fmaxf(fmaf(-d1f, xfc[j], tb), 0.0f);
    }
    psA = sc0; psB = sc1;
}

__global__ __launch_bounds__(128, 1) void snn_kernel_n(const float* __restrict__ weight,
                                                       const uint8_t* __restrict__ code,
                                                       uint8_t* __restrict__ slots,
                                                       float* __restrict__ out) {
    const int tid  = threadIdx.x;
    const int wave = tid >> 6;
    const int lane = tid & 63;
    const int row  = blockIdx.x * 2 + wave;

    float wA[CPL], wB[CPL];
    #pragma unroll
    for (int j = 0; j < CPL; ++j) {
        int col = lane * CPL + j;
        float v = (col < CIN) ? weight[row * CIN + col] : 0.0f;
        wA[j] = v; wB[j] = v;
    }

    const uint4* code4 = (const uint4*)code;
    float xf0[CPL], pf0[CPL], xf1[CPL], pf1[CPL];
    {
        uint4 c0 = code4[lane];
        decode_code(c0, xf0, pf0);
    }
    uint4 cwA = code4[64 + lane];
    uint4 cwB = make_uint4(0u, 0u, 0u, 0u);

    float memA = 0.0f, memB = 0.0f;
    bool  psA = true, psB = true;
    int p2 = 0, p3 = 0;
    int hb_m1 = 0, hb_m2 = 0;
    uint32_t myb = 0u;

    for (int u = 0; u < T_STEPS; u += 2) {
        snn_step_n(u,     row, lane, code4, slots, wA, wB,
                   xf0, pf0, xf1, pf1, cwA, cwB,
                   memA, memB, psA, psB, p2, p3, hb_m1, hb_m2, myb);
        snn_step_n(u + 1, row, lane, code4, slots, wA, wB,
                   xf1, pf1, xf0, pf0, cwB, cwA,
                   memA, memB, psA, psB, p2, p3, hb_m1, hb_m2, myb);
    }

    {
        const int kk = (p3 << 1) | p2;
        int cst;
        if (((hb_m2 >> kk) & 1) != 0) {
            cst = 1;
        } else {
            const unsigned long long* gl2 =
                (const unsigned long long*)(slots + (size_t)(T_STEPS - 2) * N_NROW);
            unsigned long long gv2;
            for (;;) {
                gv2 = __hip_atomic_load(&gl2[lane], __ATOMIC_RELAXED,
                                        __HIP_MEMORY_SCOPE_AGENT);
                bool anyset, allp;
                scan8(gv2, kk, anyset, allp);
                if (__any((int)anyset)) { cst = 1; break; }
                if (__all((int)allp)) { cst = 0; break; }
                __builtin_amdgcn_s_sleep(1);
            }
        }
        bool sr = cst ? psB : psA;
        {
            int v = T_STEPS - 1;
            if ((v & 63) == lane) myb |= (sr ? 1u : 0u) << (v >> 6);
        }
        #pragma unroll
        for (int b = 0; b < 16; ++b) {
            int s = b * 64 + lane;
            if (s < T_STEPS)
                out[(size_t)s * COUT + row] = (float)((myb >> b) & 1u);
        }
    }
}

extern "C" void kernel_launch(void* const* d_in, const int* in_sizes, int n_in,
                              void* d_out, int out_size, void* d_ws, size_t ws_size,
                              hipStream_t stream) {
    const int*   x      = (const int*)d_in[0];     // (T,1,CIN) int32
    const float* weight = (const float*)d_in[1];   // (COUT,CIN) f32
    float* out = (float*)d_out;                    // (T,1,COUT) f32

    int prep_threads = T_STEPS * 64;
    int prep_blocks = (prep_threads + 255) / 256;
    if (ws_size >= W_TOTAL) {
        uint8_t* slots = (uint8_t*)d_ws;
        uint8_t* code  = (uint8_t*)d_ws + W_CODE_OFFSET;
        prep_kernel<true><<<prep_blocks, 256, 0, stream>>>(x, code, slots);
        snn_kernel_w<<<256, 128, 0, stream>>>(weight, code, slots, out);
    } else {
        uint8_t* slots = (uint8_t*)d_ws;
        uint8_t* code  = (uint8_t*)d_ws + N_CODE_OFFSET;
        prep_kernel<false><<<prep_blocks, 256, 0, stream>>>(x, code, slots);
        snn_kernel_n<<<256, 128, 0, stream>>>(weight, code, slots, out);
    }
}

// Round 15
// 694.541 us; speedup vs baseline: 1.4387x; 1.1299x over previous
//
#include <hip/hip_runtime.h>
#include <stdint.h>

// Net_11587821765063: sequential SNN scan, T=1000 steps.
// Output = spike_out (T,1,COUT) float32 only.
//
// Round 34 (session r14): r28 champion (735us dispatch, 3x reproduced) +
// FULL-MERGE FAST PATH. Dataflow audit: when weq (wA==wB bitwise), meq
// (memA==memB float, safe: mem only feeds adds), pseq (psA==psB) all hold,
// the two d-worlds are FULLY identical: sa==sb bitwise -> s10==s00,
// s11==s01 -> hb=(s00?5:0)|(s01?10:0), mem'=sX?0:mX, update base=wA, output
// bit sprv=psA -- ALL bst-independent. Fast path (est. 70-85% of steps):
// 2 hypotheses instead of 4, no collapse selects, updates run BEFORE the
// resolve; bst feeds only the p2/p3 history chain. Bitwise-exact by
// construction (r28 expressions with operands proven bitwise-equal).
// Slow path: r28 body verbatim. Everything else (protocol, prefetch,
// epilogue) verbatim r28. Narrow-ws fallback: proven r24 narrow verbatim.

#define T_STEPS 1000
#define CIN     784
#define COUT    512
#define CPL     13            // columns per lane (64*13 = 832 >= 784)
#define VTHR_F   12500.0f
#define PROHIB_F 11250.0f

// narrow (proven) layout
#define N_NROW        512                     // 1B per row per step
#define N_CODE_OFFSET 524288                  // 512 KiB >= 512000 B of slots
// wide layout (proven r24/r28): 8B per row per step
#define W_ROWBYTES    4096                    // 512 rows * 8B stride
#define W_CODE_OFFSET 4194304                 // 4 MiB >= 4,096,000 B of slots
#define CODE_BYTES    (T_STEPS * 64 * 16)     // 1,024,000 B
#define W_TOTAL       ((size_t)W_CODE_OFFSET + (size_t)CODE_BYTES)

// ---- prep: zero slots and pack per-(t,lane) 16-byte code slot:
// byte j (j<13) encodes col = lane*13+j: bit0 = x[t][col], bits[2:1] = p.
template <bool WIDE>
__global__ __launch_bounds__(256) void prep_kernel(const int* __restrict__ x,
                                                   uint8_t* __restrict__ code,
                                                   uint8_t* __restrict__ slots) {
    int gid = blockIdx.x * blockDim.x + threadIdx.x;   // one per (t, lane)
    if (gid >= T_STEPS * 64) return;
    if constexpr (WIDE) {
        uint4 z = make_uint4(0u, 0u, 0u, 0u);
        uint4* s4 = (uint4*)slots;                      // 64000 x 64B = 4.096MB
        #pragma unroll
        for (int k = 0; k < 4; ++k) s4[(size_t)gid * 4 + k] = z;
    } else {
        ((uint2*)slots)[gid] = make_uint2(0u, 0u);      // 64000 x 8B
    }
    int t = gid >> 6;
    int lane = gid & 63;
    uint32_t wds[4] = {0u, 0u, 0u, 0u};
    #pragma unroll
    for (int j = 0; j < CPL; ++j) {
        int col = lane * CPL + j;
        uint32_t b = 0u;
        if (col < CIN) {
            int xc = x[t * CIN + col];
            int xp = (t > 0) ? x[(t - 1) * CIN + col] : 0;
            int p = xc ? 2 : ((t == 0) ? 1 : (xp ? 1 : 0));
            b = (uint32_t)((xc & 1) | (p << 1));
        }
        wds[j >> 2] |= b << ((j & 3) * 8);
    }
    ((uint4*)code)[gid] = make_uint4(wds[0], wds[1], wds[2], wds[3]);
}

// narrow scan: 8 row-bytes in one ull
__device__ __forceinline__ void scan8(unsigned long long gv, int kk,
                                      bool& anyset, bool& allp) {
    anyset = false; allp = true;
    #pragma unroll
    for (int i = 0; i < 8; ++i) {
        uint32_t b = (uint32_t)(gv >> (8 * i)) & 0xFFu;
        bool p = (b & 0xF0u) == 0xB0u;
        allp = allp && p;
        anyset = anyset || (p && (((b >> kk) & 1u) != 0u));
    }
}

// wide scan: 8 slots (8B stride), row byte is byte0 of each ull.
__device__ __forceinline__ void scan8w(const unsigned long long* g, int kk,
                                       bool& anyset, bool& allp) {
    anyset = false; allp = true;
    #pragma unroll
    for (int i = 0; i < 8; ++i) {
        uint32_t b = (uint32_t)(g[i] & 0xFFu);
        bool p = (b & 0xF0u) == 0xB0u;
        allp = allp && p;
        anyset = anyset || (p && (((b >> kk) & 1u) != 0u));
    }
}

// bfe-based decode (r27): values identical to the byte-wise decode.
__device__ __forceinline__ void decode_code(const uint4& c, float* xf, float* pf) {
    uint32_t cwd[4] = {c.x, c.y, c.z, c.w};
    #pragma unroll
    for (int j = 0; j < CPL; ++j) {
        xf[j] = (float)((cwd[j >> 2] >> ((j & 3) * 8)) & 1u);
        pf[j] = (float)((cwd[j >> 2] >> ((j & 3) * 8 + 1)) & 0x7Fu);
    }
}

// ---- fast bit-exact butterfly building blocks ----
typedef unsigned uint2ev __attribute__((ext_vector_type(2)));

__device__ __forceinline__ float pl32_sum(float v) {
    unsigned a = __builtin_bit_cast(unsigned, v);
    unsigned b = a;
#if __has_builtin(__builtin_amdgcn_permlane32_swap)
    uint2ev r = __builtin_amdgcn_permlane32_swap(a, b, false, false);
    a = r.x; b = r.y;
#else
    asm volatile("v_permlane32_swap_b32 %0, %1" : "+v"(a), "+v"(b));
#endif
    return __builtin_bit_cast(float, a) + __builtin_bit_cast(float, b);
}

__device__ __forceinline__ float pl16_sum(float v) {
    unsigned a = __builtin_bit_cast(unsigned, v);
    unsigned b = a;
#if __has_builtin(__builtin_amdgcn_permlane16_swap)
    uint2ev r = __builtin_amdgcn_permlane16_swap(a, b, false, false);
    a = r.x; b = r.y;
#else
    asm volatile("v_permlane16_swap_b32 %0, %1" : "+v"(a), "+v"(b));
#endif
    return __builtin_bit_cast(float, a) + __builtin_bit_cast(float, b);
}

template <int CTRL>
__device__ __forceinline__ float dpp_xor_sum(float v) {
    int xi = __builtin_bit_cast(int, v);
    int t = __builtin_amdgcn_update_dpp(xi, xi, CTRL, 0xF, 0xF, false);
    return v + __builtin_bit_cast(float, t);
}

// stage 4 (xor4 within 16-lane rows) in pure DPP (validated r23)
__device__ __forceinline__ float dpp_xor4_sum(float v) {
    int xi = __builtin_bit_cast(int, v);
    int t1 = __builtin_amdgcn_update_dpp(xi, xi, 0x124, 0xF, 0x5, false);
    int t2 = __builtin_amdgcn_update_dpp(t1, xi, 0x12C, 0xF, 0xA, false);
    return v + __builtin_bit_cast(float, t2);
}

// full 64-lane sum, pairing bit-identical to the validated xor butterfly
__device__ __forceinline__ float wave_sum(float v) {
    v = pl32_sum(v);                  // stage 32
    v = pl16_sum(v);                  // stage 16
    v = dpp_xor_sum<0x128>(v);        // stage 8
    v = dpp_xor4_sum(v);              // stage 4
    v = dpp_xor_sum<0x4E>(v);         // stage 2
    v = dpp_xor_sum<0xB1>(v);         // stage 1
    return v;
}

__device__ __forceinline__ int rfl(bool b) {
    return __builtin_amdgcn_readfirstlane((int)b);
}

// ======================= wide step (r28 + full-merge fast path) ===========
__device__ __forceinline__ void snn_step_w(
    int u, int row, int lane,
    const uint4* __restrict__ code4, uint8_t* __restrict__ slots,
    float (&wA)[CPL], float (&wB)[CPL],
    float (&xfc)[CPL], float (&pfc)[CPL],
    float (&xfn)[CPL], float (&pfn)[CPL],
    uint4& cwn, uint4& cwl,
    unsigned long long (&gcur)[8], unsigned long long (&gnxt)[8],
    float& memA, float& memB, bool& psA, bool& psB,
    int& p2, int& p3, int& hb_m1, int& hb_m2,
    bool& weq, uint32_t& myb)
{
    // ---- top-of-step: code load for u+2; selfdec from own history ----
    cwl = (u + 2 < T_STEPS) ? code4[(size_t)(u + 2) * 64 + lane]
                            : make_uint4(0u, 0u, 0u, 0u);
    const int kk = (p3 << 1) | p2;
    const bool selfdec = (u >= 2) && (((hb_m2 >> kk) & 1) != 0);
    const unsigned long long* gl =
        (const unsigned long long*)(slots + (size_t)(u >= 2 ? u - 2 : 0) * W_ROWBYTES);
    // gather for this step was PREFETCHED into gcur at end of step u-1.

    // ---- full-merge fast path: weq && meq && pseq -> d-worlds identical,
    // everything except the p2/p3 history is bst-independent (bit-exact:
    // r28 expressions with operands proven bitwise-equal) ----
    const bool fastc = weq && (memA == memB) && (psA == psB);
    if (rfl(fastc)) {
        float dA = 0.0f;
        #pragma unroll
        for (int j = 0; j < CPL; ++j) dA += xfc[j] * wA[j];
        float dotA = wave_sum(dA);

        decode_code(cwn, xfn, pfn);

        float sa = memA + dotA;
        float m00 = fmaxf(sa, 0.0f), m01 = fmaxf(sa - PROHIB_F, 0.0f);
        bool s00 = m00 >= VTHR_F, s01 = m01 >= VTHR_F;
        int hb = (s00 ? 5 : 0) | (s01 ? 10 : 0);   // s10==s00, s11==s01

        if (lane == 0)
            __hip_atomic_store(&slots[(size_t)u * W_ROWBYTES + (size_t)row * 8],
                               (uint8_t)(0xB0u | (uint32_t)hb),
                               __ATOMIC_RELAXED, __HIP_MEMORY_SCOPE_AGENT);

        // pre-resolve updates: sprv = psA (pseq), sc0=s00, sc1=s01
        bool sprv = psA;
        if (u >= 1) {
            int v = u - 1;
            if ((v & 63) == lane) myb |= (sprv ? 1u : 0u) << (v >> 6);
        }
        memA = s00 ? 0.0f : m00;
        memB = s01 ? 0.0f : m01;

        const bool sc_eq = (s00 == s01);
        if (rfl(sc_eq)) {
            if (rfl(s00)) {                       // spike
                #pragma unroll
                for (int j = 0; j < CPL; ++j)
                    wA[j] = fminf(pfc[j] + wA[j], 127.0f);
            } else if (rfl(sprv)) {               // depression
                #pragma unroll
                for (int j = 0; j < CPL; ++j)
                    wA[j] = fmaxf(wA[j] - xfc[j], 0.0f);
            }                                     // else: unchanged
        } else {
            float s0f = s00 ? 1.0f : 0.0f;
            float s1f = s01 ? 1.0f : 0.0f;
            float d0f = (!s00 && sprv) ? 1.0f : 0.0f;
            float d1f = (!s01 && sprv) ? 1.0f : 0.0f;
            #pragma unroll
            for (int j = 0; j < CPL; ++j) {
                float base = wA[j];
                float ta = fminf(fmaf(s0f, pfc[j], base), 127.0f);
                wA[j] = fmaxf(fmaf(-d0f, xfc[j], ta), 0.0f);
                float tb = fminf(fmaf(s1f, pfc[j], base), 127.0f);
                wB[j] = fmaxf(fmaf(-d1f, xfc[j], tb), 0.0f);
            }
        }
        weq = sc_eq;
        psA = s00; psB = s01;

        // resolve bst -- feeds ONLY p2/p3 history (verbatim protocol)
        int bst = 0;
        if (u >= 2) {
            if (selfdec) {
                bst = 1;
            } else {
                bool anyset, allp;
                scan8w(gcur, kk, anyset, allp);
                if (__any((int)anyset)) { bst = 1; }
                else if (__all((int)allp)) { bst = 0; }
                else {
                    for (;;) {
                        __builtin_amdgcn_s_sleep(1);
                        #pragma unroll
                        for (int i = 0; i < 8; ++i)
                            gcur[i] = __hip_atomic_load(&gl[8 * lane + i],
                                                        __ATOMIC_RELAXED,
                                                        __HIP_MEMORY_SCOPE_AGENT);
                        scan8w(gcur, kk, anyset, allp);
                        if (__any((int)anyset)) { bst = 1; break; }
                        if (__all((int)allp)) { bst = 0; break; }
                    }
                }
            }
        }
        p3 = p2; p2 = bst;
        hb_m2 = hb_m1; hb_m1 = hb;

        // distance-1 gated gather prefetch for step u+1 (verbatim r28)
        if (u + 1 < T_STEPS && u >= 1) {
            const int kk2 = (p3 << 1) | p2;
            if (((hb_m2 >> kk2) & 1) == 0) {
                const unsigned long long* glp =
                    (const unsigned long long*)(slots + (size_t)(u - 1) * W_ROWBYTES);
                #pragma unroll
                for (int i = 0; i < 8; ++i)
                    gnxt[i] = __hip_atomic_load(&glp[8 * lane + i],
                                                __ATOMIC_RELAXED,
                                                __HIP_MEMORY_SCOPE_AGENT);
            }
        }
        return;
    }

    // ======================= slow path: r28 verbatim =======================
    float dotA, dotB;
    if (rfl(weq)) {
        float dA = 0.0f;
        #pragma unroll
        for (int j = 0; j < CPL; ++j) dA += xfc[j] * wA[j];
        dotA = wave_sum(dA);
        dotB = dotA;                   // bitwise-identical
    } else {
        float dA = 0.0f, dB = 0.0f;
        #pragma unroll
        for (int j = 0; j < CPL; ++j) {
            dA += xfc[j] * wA[j];
            dB += xfc[j] * wB[j];
        }
        dotA = wave_sum(dA);
        dotB = wave_sum(dB);
    }

    decode_code(cwn, xfn, pfn);

    float sa = memA + dotA;
    float sb = memB + dotB;
    float m00 = fmaxf(sa, 0.0f), m01 = fmaxf(sa - PROHIB_F, 0.0f);
    float m10 = fmaxf(sb, 0.0f), m11 = fmaxf(sb - PROHIB_F, 0.0f);
    bool s00 = m00 >= VTHR_F, s01 = m01 >= VTHR_F;
    bool s10 = m10 >= VTHR_F, s11 = m11 >= VTHR_F;
    int hb = (s00 ? 1 : 0) | (s01 ? 2 : 0) | (s10 ? 4 : 0) | (s11 ? 8 : 0);

    if (lane == 0)
        __hip_atomic_store(&slots[(size_t)u * W_ROWBYTES + (size_t)row * 8],
                           (uint8_t)(0xB0u | (uint32_t)hb),
                           __ATOMIC_RELAXED, __HIP_MEMORY_SCOPE_AGENT);

    int bst = 0;
    if (u >= 2) {
        if (selfdec) {
            bst = 1;
        } else {
            bool anyset, allp;
            scan8w(gcur, kk, anyset, allp);
            if (__any((int)anyset)) { bst = 1; }
            else if (__all((int)allp)) { bst = 0; }
            else {
                for (;;) {
                    __builtin_amdgcn_s_sleep(1);       // backoff (rare path)
                    #pragma unroll
                    for (int i = 0; i < 8; ++i)
                        gcur[i] = __hip_atomic_load(&gl[8 * lane + i],
                                                    __ATOMIC_RELAXED,
                                                    __HIP_MEMORY_SCOPE_AGENT);
                    scan8w(gcur, kk, anyset, allp);
                    if (__any((int)anyset)) { bst = 1; break; }
                    if (__all((int)allp)) { bst = 0; break; }
                }
            }
        }
    }
    p3 = p2; p2 = bst;
    hb_m2 = hb_m1; hb_m1 = hb;

    bool sprv = bst ? psB : psA;
    bool sc0  = bst ? s10 : s00;
    bool sc1  = bst ? s11 : s01;
    float mc0 = bst ? m10 : m00;
    float mc1 = bst ? m11 : m01;

    if (u >= 1) {
        int v = u - 1;
        if ((v & 63) == lane) myb |= (sprv ? 1u : 0u) << (v >> 6);
    }

    memA = sc0 ? 0.0f : mc0;
    memB = sc1 ? 0.0f : mc1;

    const bool sc_eq = (sc0 == sc1);
    if (rfl(weq)) {
        if (rfl(sc_eq)) {
            if (rfl(sc0)) {                       // spike
                #pragma unroll
                for (int j = 0; j < CPL; ++j)
                    wA[j] = fminf(pfc[j] + wA[j], 127.0f);
            } else if (rfl(sprv)) {               // depression
                #pragma unroll
                for (int j = 0; j < CPL; ++j)
                    wA[j] = fmaxf(wA[j] - xfc[j], 0.0f);
            }                                     // else: unchanged
        } else {
            float s0f = sc0 ? 1.0f : 0.0f;
            float s1f = sc1 ? 1.0f : 0.0f;
            float d0f = (!sc0 && sprv) ? 1.0f : 0.0f;
            float d1f = (!sc1 && sprv) ? 1.0f : 0.0f;
            #pragma unroll
            for (int j = 0; j < CPL; ++j) {
                float base = wA[j];
                float ta = fminf(fmaf(s0f, pfc[j], base), 127.0f);
                wA[j] = fmaxf(fmaf(-d0f, xfc[j], ta), 0.0f);
                float tb = fminf(fmaf(s1f, pfc[j], base), 127.0f);
                wB[j] = fmaxf(fmaf(-d1f, xfc[j], tb), 0.0f);
            }
        }
    } else {
        if (rfl(sc_eq)) {
            if (rfl(bst != 0)) {
                if (rfl(sc0)) {
                    #pragma unroll
                    for (int j = 0; j < CPL; ++j)
                        wA[j] = fminf(pfc[j] + wB[j], 127.0f);
                } else if (rfl(sprv)) {
                    #pragma unroll
                    for (int j = 0; j < CPL; ++j)
                        wA[j] = fmaxf(wB[j] - xfc[j], 0.0f);
                } else {
                    #pragma unroll
                    for (int j = 0; j < CPL; ++j)
                        wA[j] = wB[j];
                }
            } else {
                if (rfl(sc0)) {
                    #pragma unroll
                    for (int j = 0; j < CPL; ++j)
                        wA[j] = fminf(pfc[j] + wA[j], 127.0f);
                } else if (rfl(sprv)) {
                    #pragma unroll
                    for (int j = 0; j < CPL; ++j)
                        wA[j] = fmaxf(wA[j] - xfc[j], 0.0f);
                }                                 // else: unchanged
            }
        } else {
            float s0f = sc0 ? 1.0f : 0.0f;
            float s1f = sc1 ? 1.0f : 0.0f;
            float d0f = (!sc0 && sprv) ? 1.0f : 0.0f;
            float d1f = (!sc1 && sprv) ? 1.0f : 0.0f;
            if (rfl(bst != 0)) {
                #pragma unroll
                for (int j = 0; j < CPL; ++j) {
                    float base = wB[j];
                    float ta = fminf(fmaf(s0f, pfc[j], base), 127.0f);
                    wA[j] = fmaxf(fmaf(-d0f, xfc[j], ta), 0.0f);
                    float tb = fminf(fmaf(s1f, pfc[j], base), 127.0f);
                    wB[j] = fmaxf(fmaf(-d1f, xfc[j], tb), 0.0f);
                }
            } else {
                #pragma unroll
                for (int j = 0; j < CPL; ++j) {
                    float base = wA[j];
                    float ta = fminf(fmaf(s0f, pfc[j], base), 127.0f);
                    wA[j] = fmaxf(fmaf(-d0f, xfc[j], ta), 0.0f);
                    float tb = fminf(fmaf(s1f, pfc[j], base), 127.0f);
                    wB[j] = fmaxf(fmaf(-d1f, xfc[j], tb), 0.0f);
                }
            }
        }
    }
    weq = sc_eq;
    psA = sc0; psB = sc1;

    if (u + 1 < T_STEPS && u >= 1) {          // (u+1) >= 2
        const int kk2 = (p3 << 1) | p2;
        if (((hb_m2 >> kk2) & 1) == 0) {
            const unsigned long long* glp =
                (const unsigned long long*)(slots + (size_t)(u - 1) * W_ROWBYTES);
            #pragma unroll
            for (int i = 0; i < 8; ++i)
                gnxt[i] = __hip_atomic_load(&glp[8 * lane + i], __ATOMIC_RELAXED,
                                            __HIP_MEMORY_SCOPE_AGENT);
        }
    }
}

__global__ __launch_bounds__(128, 1) void snn_kernel_w(const float* __restrict__ weight,
                                                       const uint8_t* __restrict__ code,
                                                       uint8_t* __restrict__ slots,
                                                       float* __restrict__ out) {
    const int tid  = threadIdx.x;
    const int wave = tid >> 6;
    const int lane = tid & 63;
    const int row  = blockIdx.x * 2 + wave;    // 512 autonomous waves, 256 CUs

    float wA[CPL], wB[CPL];
    #pragma unroll
    for (int j = 0; j < CPL; ++j) {
        int col = lane * CPL + j;
        float v = (col < CIN) ? weight[row * CIN + col] : 0.0f;
        wA[j] = v; wB[j] = v;
    }

    const uint4* code4 = (const uint4*)code;

    float xf0[CPL], pf0[CPL], xf1[CPL], pf1[CPL];
    {
        uint4 c0 = code4[lane];
        decode_code(c0, xf0, pf0);
    }
    uint4 cwA = code4[64 + lane];
    uint4 cwB = make_uint4(0u, 0u, 0u, 0u);

    unsigned long long gA[8], gB[8];
    #pragma unroll
    for (int i = 0; i < 8; ++i) { gA[i] = 0xB0B0B0B0B0B0B0B0ull; gB[i] = gA[i]; }

    float memA = 0.0f, memB = 0.0f;
    bool  psA = true, psB = true;          // spike(-1)=true quirk
    int p2 = 0, p3 = 0;
    int hb_m1 = 0, hb_m2 = 0;
    bool weq = true;                       // wA==wB at start
    uint32_t myb = 0u;

    for (int u = 0; u < T_STEPS; u += 2) {
        snn_step_w(u,     row, lane, code4, slots, wA, wB,
                   xf0, pf0, xf1, pf1, cwA, cwB, gA, gB,
                   memA, memB, psA, psB, p2, p3, hb_m1, hb_m2, weq, myb);
        snn_step_w(u + 1, row, lane, code4, slots, wA, wB,
                   xf1, pf1, xf0, pf0, cwB, cwA, gB, gA,
                   memA, memB, psA, psB, p2, p3, hb_m1, hb_m2, weq, myb);
    }

    // ---- epilogue (verbatim wide) ----
    {
        const int kk = (p3 << 1) | p2;
        int cst;
        if (((hb_m2 >> kk) & 1) != 0) {
            cst = 1;
        } else {
            const unsigned long long* gl2 =
                (const unsigned long long*)(slots + (size_t)(T_STEPS - 2) * W_ROWBYTES);
            unsigned long long g2[8];
            for (;;) {
                #pragma unroll
                for (int i = 0; i < 8; ++i)
                    g2[i] = __hip_atomic_load(&gl2[8 * lane + i],
                                              __ATOMIC_RELAXED,
                                              __HIP_MEMORY_SCOPE_AGENT);
                bool anyset, allp;
                scan8w(g2, kk, anyset, allp);
                if (__any((int)anyset)) { cst = 1; break; }
                if (__all((int)allp)) { cst = 0; break; }
                __builtin_amdgcn_s_sleep(1);
            }
        }
        bool sr = cst ? psB : psA;
        {
            int v = T_STEPS - 1;
            if ((v & 63) == lane) myb |= (sr ? 1u : 0u) << (v >> 6);
        }
        #pragma unroll
        for (int b = 0; b < 16; ++b) {
            int s = b * 64 + lane;
            if (s < T_STEPS)
                out[(size_t)s * COUT + row] = (float)((myb >> b) & 1u);
        }
    }
}

// ======================= narrow fallback (proven r24 narrow) =======================
__device__ __forceinline__ void snn_step_n(
    int u, int row, int lane,
    const uint4* __restrict__ code4, uint8_t* __restrict__ slots,
    float (&wA)[CPL], float (&wB)[CPL],
    float (&xfc)[CPL], float (&pfc)[CPL],
    float (&xfn)[CPL], float (&pfn)[CPL],
    uint4& cwn, uint4& cwl,
    float& memA, float& memB, bool& psA, bool& psB,
    int& p2, int& p3, int& hb_m1, int& hb_m2,
    uint32_t& myb)
{
    cwl = (u + 2 < T_STEPS) ? code4[(size_t)(u + 2) * 64 + lane]
                            : make_uint4(0u, 0u, 0u, 0u);
    const int kk = (p3 << 1) | p2;
    const bool selfdec = (u >= 2) && (((hb_m2 >> kk) & 1) != 0);
    const unsigned long long* gl =
        (const unsigned long long*)(slots + (size_t)(u >= 2 ? u - 2 : 0) * N_NROW);
    unsigned long long gv = 0xB0B0B0B0B0B0B0B0ull;
    if (u >= 2 && !selfdec)
        gv = __hip_atomic_load(&gl[lane], __ATOMIC_RELAXED,
                               __HIP_MEMORY_SCOPE_AGENT);

    float dA = 0.0f, dB = 0.0f;
    #pragma unroll
    for (int j = 0; j < CPL; ++j) { dA += xfc[j] * wA[j]; dB += xfc[j] * wB[j]; }
    float dotA = wave_sum(dA);
    float dotB = wave_sum(dB);

    decode_code(cwn, xfn, pfn);

    float sa = memA + dotA;
    float sb = memB + dotB;
    float m00 = fmaxf(sa, 0.0f), m01 = fmaxf(sa - PROHIB_F, 0.0f);
    float m10 = fmaxf(sb, 0.0f), m11 = fmaxf(sb - PROHIB_F, 0.0f);
    bool s00 = m00 >= VTHR_F, s01 = m01 >= VTHR_F;
    bool s10 = m10 >= VTHR_F, s11 = m11 >= VTHR_F;
    int hb = (s00 ? 1 : 0) | (s01 ? 2 : 0) | (s10 ? 4 : 0) | (s11 ? 8 : 0);

    if (lane == 0)
        __hip_atomic_store(&slots[(size_t)u * N_NROW + row],
                           (uint8_t)(0xB0u | (uint32_t)hb),
                           __ATOMIC_RELAXED, __HIP_MEMORY_SCOPE_AGENT);

    int bst = 0;
    if (u >= 2) {
        if (selfdec) {
            bst = 1;
        } else {
            for (;;) {
                bool anyset, allp;
                scan8(gv, kk, anyset, allp);
                if (__any((int)anyset)) { bst = 1; break; }
                if (__all((int)allp)) { bst = 0; break; }
                __builtin_amdgcn_s_sleep(1);
                gv = __hip_atomic_load(&gl[lane], __ATOMIC_RELAXED,
                                       __HIP_MEMORY_SCOPE_AGENT);
            }
        }
    }
    p3 = p2; p2 = bst;
    hb_m2 = hb_m1; hb_m1 = hb;

    bool sprv = bst ? psB : psA;
    bool sc0  = bst ? s10 : s00;
    bool sc1  = bst ? s11 : s01;
    float mc0 = bst ? m10 : m00;
    float mc1 = bst ? m11 : m01;

    if (u >= 1) {
        int v = u - 1;
        if ((v & 63) == lane) myb |= (sprv ? 1u : 0u) << (v >> 6);
    }

    memA = sc0 ? 0.0f : mc0;
    memB = sc1 ? 0.0f : mc1;

    float s0f = sc0 ? 1.0f : 0.0f;
    float s1f = sc1 ? 1.0f : 0.0f;
    float d0f = (!sc0 && sprv) ? 1.0f : 0.0f;
    float d1f = (!sc1 && sprv) ? 1.0f : 0.0f;
    #pragma unroll
    for (int j = 0; j < CPL; ++j) {
        float base = bst ? wB[j] : wA[j];
        float ta = fminf(fmaf(s0f, pfc[j], base), 127.0f);
        wA[j] = fmaxf(fmaf(-d0f, xfc[j], ta), 0.0f);
        float tb = fminf(fmaf(s1f, pfc[j], base), 127.0f);
        wB[j] = fmaxf(fmaf(-d1f, xfc[j], tb), 0.0f);
    }
    psA = sc0; psB = sc1;
}

__global__ __launch_bounds__(128, 1) void snn_kernel_n(const float* __restrict__ weight,
                                                       const uint8_t* __restrict__ code,
                                                       uint8_t* __restrict__ slots,
                                                       float* __restrict__ out) {
    const int tid  = threadIdx.x;
    const int wave = tid >> 6;
    const int lane = tid & 63;
    const int row  = blockIdx.x * 2 + wave;

    float wA[CPL], wB[CPL];
    #pragma unroll
    for (int j = 0; j < CPL; ++j) {
        int col = lane * CPL + j;
        float v = (col < CIN) ? weight[row * CIN + col] : 0.0f;
        wA[j] = v; wB[j] = v;
    }

    const uint4* code4 = (const uint4*)code;
    float xf0[CPL], pf0[CPL], xf1[CPL], pf1[CPL];
    {
        uint4 c0 = code4[lane];
        decode_code(c0, xf0, pf0);
    }
    uint4 cwA = code4[64 + lane];
    uint4 cwB = make_uint4(0u, 0u, 0u, 0u);

    float memA = 0.0f, memB = 0.0f;
    bool  psA = true, psB = true;
    int p2 = 0, p3 = 0;
    int hb_m1 = 0, hb_m2 = 0;
    uint32_t myb = 0u;

    for (int u = 0; u < T_STEPS; u += 2) {
        snn_step_n(u,     row, lane, code4, slots, wA, wB,
                   xf0, pf0, xf1, pf1, cwA, cwB,
                   memA, memB, psA, psB, p2, p3, hb_m1, hb_m2, myb);
        snn_step_n(u + 1, row, lane, code4, slots, wA, wB,
                   xf1, pf1, xf0, pf0, cwB, cwA,
                   memA, memB, psA, psB, p2, p3, hb_m1, hb_m2, myb);
    }

    {
        const int kk = (p3 << 1) | p2;
        int cst;
        if (((hb_m2 >> kk) & 1) != 0) {
            cst = 1;
        } else {
            const unsigned long long* gl2 =
                (const unsigned long long*)(slots + (size_t)(T_STEPS - 2) * N_NROW);
            unsigned long long gv2;
            for (;;) {
                gv2 = __hip_atomic_load(&gl2[lane], __ATOMIC_RELAXED,
                                        __HIP_MEMORY_SCOPE_AGENT);
                bool anyset, allp;
                scan8(gv2, kk, anyset, allp);
                if (__any((int)anyset)) { cst = 1; break; }
                if (__all((int)allp)) { cst = 0; break; }
                __builtin_amdgcn_s_sleep(1);
            }
        }
        bool sr = cst ? psB : psA;
        {
            int v = T_STEPS - 1;
            if ((v & 63) == lane) myb |= (sr ? 1u : 0u) << (v >> 6);
        }
        #pragma unroll
        for (int b = 0; b < 16; ++b) {
            int s = b * 64 + lane;
            if (s < T_STEPS)
                out[(size_t)s * COUT + row] = (float)((myb >> b) & 1u);
        }
    }
}

extern "C" void kernel_launch(void* const* d_in, const int* in_sizes, int n_in,
                              void* d_out, int out_size, void* d_ws, size_t ws_size,
                              hipStream_t stream) {
    const int*   x      = (const int*)d_in[0];     // (T,1,CIN) int32
    const float* weight = (const float*)d_in[1];   // (COUT,CIN) f32
    float* out = (float*)d_out;                    // (T,1,COUT) f32

    int prep_threads = T_STEPS * 64;
    int prep_blocks = (prep_threads + 255) / 256;
    if (ws_size >= W_TOTAL) {
        uint8_t* slots = (uint8_t*)d_ws;
        uint8_t* code  = (uint8_t*)d_ws + W_CODE_OFFSET;
        prep_kernel<true><<<prep_blocks, 256, 0, stream>>>(x, code, slots);
        snn_kernel_w<<<256, 128, 0, stream>>>(weight, code, slots, out);
    } else {
        uint8_t* slots = (uint8_t*)d_ws;
        uint8_t* code  = (uint8_t*)d_ws + N_CODE_OFFSET;
        prep_kernel<false><<<prep_blocks, 256, 0, stream>>>(x, code, slots);
        snn_kernel_n<<<256, 128, 0, stream>>>(weight, code, slots, out);
    }
}